// Round 2
// baseline (422.457 us; speedup 1.0000x reference)
//
#include <hip/hip_runtime.h>
#include <hip/hip_bf16.h>

typedef __hip_bfloat16 bf16;

#define N_NODES 20000
#define N_EDGES 320000
#define CSTF 1e-5f

__device__ __forceinline__ float b2f(bf16 v) { return __bfloat162float(v); }

// dtype-adaptive loads (flag is wave-uniform -> branch is free)
__device__ __forceinline__ float ldf(const void* p, int i, bool bf) {
    return bf ? __bfloat162float(((const bf16*)p)[i]) : ((const float*)p)[i];
}
__device__ __forceinline__ int ldi(const void* p, int i, bool w64) {
    return w64 ? (int)((const long long*)p)[i] : ((const int*)p)[i];
}

// ---------------------------------------------------------------------------
// Dtype detection.
// cnt[0] += #(uint16 with exponent bits all-ones) in bf16-view of x:
//          genuine bf16 x~N(0,1) -> 0;  fp32-as-bf16 -> ~2500 (low halves).
// cnt[1] |= OR of odd uint32 words of edge_index (first 640000 uint32s):
//          int64 values in [0,2^31) -> all hi-words 0 -> OR==0;  int32 -> !=0.
__global__ void k_detect(const unsigned short* __restrict__ xs,
                         const unsigned int* __restrict__ eis,
                         int* __restrict__ cnt) {
    int t = blockIdx.x * blockDim.x + threadIdx.x;
    int nthr = gridDim.x * blockDim.x;
    int bad = 0;
    for (int i = t; i < N_NODES * 64; i += nthr) {
        unsigned short u = xs[i];
        if (((u >> 7) & 0xFF) == 0xFF) bad++;
    }
    unsigned int orv = 0;
    for (int i = t; i < N_EDGES; i += nthr) orv |= eis[2 * i + 1];
    if (bad) atomicAdd(&cnt[0], bad);
    if (orv) atomicOr((unsigned int*)&cnt[1], orv);
}

// ---------------------------------------------------------------------------
__global__ void k_deg(const void* __restrict__ ei, int* __restrict__ deg,
                      const int* __restrict__ cnt) {
    bool i64 = (cnt[1] == 0);
    int e = blockIdx.x * blockDim.x + threadIdx.x;
    if (e < N_EDGES) atomicAdd(&deg[ldi(ei, N_EDGES + e, i64)], 1);
}

__global__ void k_deginv(const int* __restrict__ deg, float* __restrict__ deg_inv) {
    int n = blockIdx.x * blockDim.x + threadIdx.x;
    if (n < N_NODES) {
        int d = deg[n];
        deg_inv[n] = d > 0 ? rsqrtf((float)d) : 0.0f;
    }
}

// Exclusive scan of deg -> rowptr (single block)
__global__ __launch_bounds__(1024) void k_scan(const int* __restrict__ deg, int* __restrict__ rowptr) {
    __shared__ int part[1024];
    const int t = threadIdx.x;
    const int CH = (N_NODES + 1023) / 1024;  // 20
    int base = t * CH;
    int s = 0;
    for (int i = 0; i < CH; i++) {
        int idx = base + i;
        if (idx < N_NODES) s += deg[idx];
    }
    part[t] = s;
    __syncthreads();
    for (int off = 1; off < 1024; off <<= 1) {
        int v = (t >= off) ? part[t - off] : 0;
        __syncthreads();
        part[t] += v;
        __syncthreads();
    }
    int ex = (t == 0) ? 0 : part[t - 1];
    for (int i = 0; i < CH; i++) {
        int idx = base + i;
        if (idx < N_NODES) { rowptr[idx] = ex; ex += deg[idx]; }
    }
    if (t == 1023) rowptr[N_NODES] = part[1023];
}

__global__ void k_fill(const void* __restrict__ ei,
                       const float* __restrict__ deg_inv, const int* __restrict__ rowptr,
                       int* __restrict__ fill, int* __restrict__ csr_src, float* __restrict__ csr_w,
                       const int* __restrict__ cnt) {
    bool i64 = (cnt[1] == 0);
    int e = blockIdx.x * blockDim.x + threadIdx.x;
    if (e < N_EDGES) {
        int r = ldi(ei, e, i64);
        int c = ldi(ei, N_EDGES + e, i64);
        int slot = rowptr[c] + atomicAdd(&fill[c], 1);
        csr_src[slot] = r;
        csr_w[slot] = deg_inv[r] * deg_inv[c];
    }
}

// ---------------------------------------------------------------------------
// QKV projection: Q = 1+elu(xWq+bq), K = 1+elu(xWk+bk), V = xWv+bv  (fp32 out)
__global__ __launch_bounds__(256) void k_qkv(const void* __restrict__ x,
                                             const void* __restrict__ Wq, const void* __restrict__ bq,
                                             const void* __restrict__ Wk, const void* __restrict__ bk,
                                             const void* __restrict__ Wv, const void* __restrict__ bv,
                                             float* __restrict__ Q, float* __restrict__ K0,
                                             float* __restrict__ V, const int* __restrict__ cnt) {
    __shared__ float sWq[64 * 64];
    __shared__ float sWk[64 * 64];
    __shared__ float sWv[64 * 64];
    __shared__ float sx[4][64];
    const bool bf = (cnt[0] < 16);
    const int t = threadIdx.x;
    for (int i = t; i < 4096; i += 256) {
        sWq[i] = ldf(Wq, i, bf);
        sWk[i] = ldf(Wk, i, bf);
        sWv[i] = ldf(Wv, i, bf);
    }
    __syncthreads();
    const int lane = t & 63, sub = t >> 6;
    const float bqv = ldf(bq, lane, bf), bkv = ldf(bk, lane, bf), bvv = ldf(bv, lane, bf);
    const int npb = (N_NODES + gridDim.x - 1) / gridDim.x;
    const int n0 = blockIdx.x * npb;
    const int n1 = min(n0 + npb, N_NODES);
    for (int nb = n0; nb < n1; nb += 4) {
        int n = nb + sub;
        __syncthreads();
        if (n < n1) sx[sub][lane] = ldf(x, n * 64 + lane, bf);
        __syncthreads();
        if (n < n1) {
            float q = bqv, k = bkv, v = bvv;
#pragma unroll 16
            for (int kk = 0; kk < 64; kk++) {
                float xv = sx[sub][kk];
                q += xv * sWq[kk * 64 + lane];
                k += xv * sWk[kk * 64 + lane];
                v += xv * sWv[kk * 64 + lane];
            }
            Q[n * 64 + lane]  = q > 0.0f ? q + 1.0f : __expf(q);
            K0[n * 64 + lane] = k > 0.0f ? k + 1.0f : __expf(k);
            V[n * 64 + lane]  = v;
        }
    }
}

// ---------------------------------------------------------------------------
// Hop 1: M1[n,h,i,j] = sum_{e:col=n} w * K0[src,h,i] * V[src,h,j];  K1[n] = sum w*K0[src]
// One wave per node. Lane l owns (i=l>>3, j=l&7) for all 8 heads.
__global__ __launch_bounds__(64) void k_hop1(const float* __restrict__ K0, const float* __restrict__ V,
                                             const int* __restrict__ rowptr,
                                             const int* __restrict__ csr_src,
                                             const float* __restrict__ csr_w,
                                             float* __restrict__ M1, float* __restrict__ K1) {
    const int n = blockIdx.x;
    const int l = threadIdx.x;
    const int i = l >> 3, j = l & 7;
    float acc[8] = {0, 0, 0, 0, 0, 0, 0, 0};
    float kacc = 0.0f;
    const int s0 = rowptr[n], s1 = rowptr[n + 1];
    for (int s = s0; s < s1; s++) {
        int src = csr_src[s];
        float w = csr_w[s];
        float kreg = K0[src * 64 + l];
        float vreg = V[src * 64 + l];
        kacc += w * kreg;
#pragma unroll
        for (int h = 0; h < 8; h++) {
            float kv = __shfl(kreg, h * 8 + i);
            float vv = __shfl(vreg, h * 8 + j);
            acc[h] += w * kv * vv;
        }
    }
#pragma unroll
    for (int h = 0; h < 8; h++) M1[(size_t)n * 512 + h * 64 + l] = acc[h];
    K1[n * 64 + l] = kacc;
}

// ---------------------------------------------------------------------------
// Hop 2 (fused, no M2):
//   H2[n,h,j] = sum_{e:col=n} w * sum_i Q[n,h,i]*M1[src,h,i,j]
//   C2[n,h]   = sum_{e:col=n} w * sum_i Q[n,h,i]*K1[src,h,i]  (+CST stored)
// One wave per node. Lane l owns (h=l>>3, i=l&7); reads contiguous 8 floats of M1 row.
__global__ __launch_bounds__(64) void k_hop2(const float* __restrict__ Q, const float* __restrict__ M1,
                                             const float* __restrict__ K1,
                                             const int* __restrict__ rowptr,
                                             const int* __restrict__ csr_src,
                                             const float* __restrict__ csr_w,
                                             float* __restrict__ H2, float* __restrict__ C2) {
    const int n = blockIdx.x;
    const int l = threadIdx.x;
    const float qreg = Q[n * 64 + l];
    float acc[8] = {0, 0, 0, 0, 0, 0, 0, 0};
    float cacc = 0.0f;
    const int s0 = rowptr[n], s1 = rowptr[n + 1];
    for (int s = s0; s < s1; s++) {
        int src = csr_src[s];
        float w = csr_w[s];
        const float4* mp = (const float4*)&M1[(size_t)src * 512 + l * 8];
        float4 m0 = mp[0];
        float4 m1 = mp[1];
        float wq = w * qreg;
        acc[0] += wq * m0.x; acc[1] += wq * m0.y; acc[2] += wq * m0.z; acc[3] += wq * m0.w;
        acc[4] += wq * m1.x; acc[5] += wq * m1.y; acc[6] += wq * m1.z; acc[7] += wq * m1.w;
        cacc += wq * K1[src * 64 + l];
    }
#pragma unroll
    for (int d = 1; d < 8; d <<= 1) {
#pragma unroll
        for (int j = 0; j < 8; j++) acc[j] += __shfl_xor(acc[j], d);
        cacc += __shfl_xor(cacc, d);
    }
    const int i = l & 7;
    float hv = 0.0f;
#pragma unroll
    for (int j = 0; j < 8; j++) hv = (j == i) ? acc[j] : hv;
    H2[n * 64 + l] = hv;
    if (i == 0) C2[n * 8 + (l >> 3)] = cacc + CSTF;
}

// ---------------------------------------------------------------------------
// Finalize: H1 = Q.M1[n], C1 = Q.K1[n]; hidden = hw0*V + g1*H1/C1 + g2*H2/C2; out = hidden@Wo + bo
__global__ __launch_bounds__(64) void k_final(const float* __restrict__ Q, const float* __restrict__ M1,
                                              const float* __restrict__ K1, const float* __restrict__ V,
                                              const float* __restrict__ H2, const float* __restrict__ C2,
                                              const void* __restrict__ Wo, const void* __restrict__ bo,
                                              const void* __restrict__ hopwise,
                                              const void* __restrict__ headwise,
                                              void* __restrict__ out, const int* __restrict__ cnt) {
    const bool bf = (cnt[0] < 16);
    const int n = blockIdx.x;
    const int l = threadIdx.x;
    const int h = l >> 3, i = l & 7;
    const float qreg = Q[n * 64 + l];
    const float4* mp = (const float4*)&M1[(size_t)n * 512 + l * 8];
    float4 m0 = mp[0];
    float4 m1 = mp[1];
    float a[8];
    a[0] = qreg * m0.x; a[1] = qreg * m0.y; a[2] = qreg * m0.z; a[3] = qreg * m0.w;
    a[4] = qreg * m1.x; a[5] = qreg * m1.y; a[6] = qreg * m1.z; a[7] = qreg * m1.w;
    float c1 = qreg * K1[n * 64 + l];
#pragma unroll
    for (int d = 1; d < 8; d <<= 1) {
#pragma unroll
        for (int j = 0; j < 8; j++) a[j] += __shfl_xor(a[j], d);
        c1 += __shfl_xor(c1, d);
    }
    float h1 = 0.0f;
#pragma unroll
    for (int j = 0; j < 8; j++) h1 = (j == i) ? a[j] : h1;
    float h2 = H2[n * 64 + l];
    float c2 = C2[n * 8 + h];  // already includes CST

    float hw0 = ldf(hopwise, 0, bf), hw1 = ldf(hopwise, 1, bf), hw2 = ldf(hopwise, 2, bf);
    float s0 = 0.0f, s1 = 0.0f;
#pragma unroll
    for (int hh = 0; hh < 8; hh++) {
        s0 += __expf(ldf(headwise, hh * 2 + 0, bf));
        s1 += __expf(ldf(headwise, hh * 2 + 1, bf));
    }
    float g1 = hw1 * __expf(ldf(headwise, h * 2 + 0, bf)) / s0;
    float g2 = hw2 * __expf(ldf(headwise, h * 2 + 1, bf)) / s1;

    float hidden = hw0 * V[n * 64 + l] + g1 * h1 / (c1 + CSTF) + g2 * h2 / c2;

    // output projection: out[n,c] = sum_k hidden_k * Wo[k,c] + bo[c]; lane l is column c
    float o = ldf(bo, l, bf);
#pragma unroll 16
    for (int k = 0; k < 64; k++) {
        float hk = __shfl(hidden, k);
        o += hk * ldf(Wo, k * 64 + l, bf);
    }
    if (bf) ((bf16*)out)[n * 64 + l] = __float2bfloat16(o);
    else    ((float*)out)[n * 64 + l] = o;
}

// ---------------------------------------------------------------------------
extern "C" void kernel_launch(void* const* d_in, const int* in_sizes, int n_in,
                              void* d_out, int out_size, void* d_ws, size_t ws_size,
                              hipStream_t stream) {
    const void* x        = d_in[0];
    const void* ei       = d_in[1];
    const void* Wq       = d_in[3];
    const void* bq       = d_in[4];
    const void* Wk       = d_in[5];
    const void* bk       = d_in[6];
    const void* Wv       = d_in[7];
    const void* bv       = d_in[8];
    const void* Wo       = d_in[9];
    const void* bo       = d_in[10];
    const void* hopwise  = d_in[11];
    const void* headwise = d_in[12];

    char* p = (char*)d_ws;
    auto alloc = [&](size_t bytes) {
        void* r = (void*)p;
        p += (bytes + 255) & ~(size_t)255;
        return r;
    };
    float* Q       = (float*)alloc((size_t)N_NODES * 64 * 4);
    float* K0      = (float*)alloc((size_t)N_NODES * 64 * 4);
    float* V       = (float*)alloc((size_t)N_NODES * 64 * 4);
    float* K1      = (float*)alloc((size_t)N_NODES * 64 * 4);
    float* H2      = (float*)alloc((size_t)N_NODES * 64 * 4);
    float* C2      = (float*)alloc((size_t)N_NODES * 8 * 4);
    float* deg_inv = (float*)alloc((size_t)N_NODES * 4);
    float* M1      = (float*)alloc((size_t)N_NODES * 512 * 4);
    float* csr_w   = (float*)alloc((size_t)N_EDGES * 4);
    int* csr_src   = (int*)alloc((size_t)N_EDGES * 4);
    int* deg       = (int*)alloc((size_t)N_NODES * 4);
    int* fill      = (int*)alloc((size_t)N_NODES * 4);
    int* rowptr    = (int*)alloc((size_t)(N_NODES + 1) * 4);
    int* cnt       = (int*)alloc(2 * 4);

    hipMemsetAsync(deg, 0, (size_t)N_NODES * 4, stream);
    hipMemsetAsync(fill, 0, (size_t)N_NODES * 4, stream);
    hipMemsetAsync(cnt, 0, 2 * 4, stream);

    const int EB = (N_EDGES + 255) / 256;
    const int NB = (N_NODES + 255) / 256;

    k_detect<<<64, 256, 0, stream>>>((const unsigned short*)x, (const unsigned int*)ei, cnt);
    k_deg<<<EB, 256, 0, stream>>>(ei, deg, cnt);
    k_deginv<<<NB, 256, 0, stream>>>(deg, deg_inv);
    k_scan<<<1, 1024, 0, stream>>>(deg, rowptr);
    k_fill<<<EB, 256, 0, stream>>>(ei, deg_inv, rowptr, fill, csr_src, csr_w, cnt);
    k_qkv<<<160, 256, 0, stream>>>(x, Wq, bq, Wk, bk, Wv, bv, Q, K0, V, cnt);
    k_hop1<<<N_NODES, 64, 0, stream>>>(K0, V, rowptr, csr_src, csr_w, M1, K1);
    k_hop2<<<N_NODES, 64, 0, stream>>>(Q, M1, K1, rowptr, csr_src, csr_w, H2, C2);
    k_final<<<N_NODES, 64, 0, stream>>>(Q, M1, K1, V, H2, C2, Wo, bo, hopwise, headwise, d_out, cnt);
}

// Round 3
// 338.679 us; speedup vs baseline: 1.2474x; 1.2474x over previous
//
#include <hip/hip_runtime.h>
#include <hip/hip_bf16.h>

typedef __hip_bfloat16 bf16;

#define N_NODES 20000
#define N_EDGES 320000
#define CSTF 1e-5f

__device__ __forceinline__ float b2f(bf16 v) { return __bfloat162float(v); }
// bf16 (stored as ushort) <-> f32 via bit ops: bf16->f32 is just <<16
__device__ __forceinline__ float us2f(unsigned short u) { return __uint_as_float(((unsigned int)u) << 16); }
__device__ __forceinline__ unsigned short f2us(float f) { return __bfloat16_as_ushort(__float2bfloat16(f)); }
__device__ __forceinline__ float2 upk(unsigned int u) {
    float2 r; r.x = __uint_as_float(u << 16); r.y = __uint_as_float(u & 0xFFFF0000u); return r;
}
__device__ __forceinline__ unsigned int pk(float a, float b) {
    return (unsigned int)f2us(a) | ((unsigned int)f2us(b) << 16);
}

// dtype-adaptive loads (flag is wave-uniform -> branch is free)
__device__ __forceinline__ float ldf(const void* p, int i, bool bf) {
    return bf ? __bfloat162float(((const bf16*)p)[i]) : ((const float*)p)[i];
}
__device__ __forceinline__ int ldi(const void* p, int i, bool w64) {
    return w64 ? (int)((const long long*)p)[i] : ((const int*)p)[i];
}

// ---------------------------------------------------------------------------
// Dtype detection (see R1 notes): cnt[0] = #NaN-exponent ushorts in bf16-view
// of x (fp32 data -> thousands; real bf16 -> 0). cnt[1] = OR of odd uint32
// words of edge_index (int64 -> 0; int32 -> nonzero).
__global__ void k_detect(const unsigned int* __restrict__ xs,
                         const unsigned int* __restrict__ eis,
                         int* __restrict__ cnt) {
    int t = blockIdx.x * blockDim.x + threadIdx.x;
    int nthr = gridDim.x * blockDim.x;
    int bad = 0;
    for (int i = t; i < N_NODES * 32; i += nthr) {  // 640000 uint32 = 1.28M ushort
        unsigned int w = xs[i];
        if (((w >> 7)  & 0xFFu) == 0xFFu) bad++;
        if (((w >> 23) & 0xFFu) == 0xFFu) bad++;
    }
    unsigned int orv = 0;
    const uint2* e2 = (const uint2*)eis;
    for (int i = t; i < N_EDGES; i += nthr) orv |= e2[i].y;
    if (bad) atomicAdd(&cnt[0], bad);
    if (orv) atomicOr((unsigned int*)&cnt[1], orv);
}

// ---------------------------------------------------------------------------
__global__ void k_deg(const void* __restrict__ ei, int* __restrict__ deg,
                      const int* __restrict__ cnt) {
    bool i64 = (cnt[1] == 0);
    int e = blockIdx.x * blockDim.x + threadIdx.x;
    if (e < N_EDGES) atomicAdd(&deg[ldi(ei, N_EDGES + e, i64)], 1);
}

__global__ void k_deginv(const int* __restrict__ deg, float* __restrict__ deg_inv) {
    int n = blockIdx.x * blockDim.x + threadIdx.x;
    if (n < N_NODES) {
        int d = deg[n];
        deg_inv[n] = d > 0 ? rsqrtf((float)d) : 0.0f;
    }
}

// Exclusive scan of deg -> rowptr (single block)
__global__ __launch_bounds__(1024) void k_scan(const int* __restrict__ deg, int* __restrict__ rowptr) {
    __shared__ int part[1024];
    const int t = threadIdx.x;
    const int CH = (N_NODES + 1023) / 1024;  // 20
    int base = t * CH;
    int s = 0;
    for (int i = 0; i < CH; i++) {
        int idx = base + i;
        if (idx < N_NODES) s += deg[idx];
    }
    part[t] = s;
    __syncthreads();
    for (int off = 1; off < 1024; off <<= 1) {
        int v = (t >= off) ? part[t - off] : 0;
        __syncthreads();
        part[t] += v;
        __syncthreads();
    }
    int ex = (t == 0) ? 0 : part[t - 1];
    for (int i = 0; i < CH; i++) {
        int idx = base + i;
        if (idx < N_NODES) { rowptr[idx] = ex; ex += deg[idx]; }
    }
    if (t == 1023) rowptr[N_NODES] = part[1023];
}

__global__ void k_fill(const void* __restrict__ ei,
                       const float* __restrict__ deg_inv, const int* __restrict__ rowptr,
                       int* __restrict__ fill, int* __restrict__ csr_src, float* __restrict__ csr_w,
                       const int* __restrict__ cnt) {
    bool i64 = (cnt[1] == 0);
    int e = blockIdx.x * blockDim.x + threadIdx.x;
    if (e < N_EDGES) {
        int r = ldi(ei, e, i64);
        int c = ldi(ei, N_EDGES + e, i64);
        int slot = rowptr[c] + atomicAdd(&fill[c], 1);
        csr_src[slot] = r;
        csr_w[slot] = deg_inv[r] * deg_inv[c];
    }
}

// ---------------------------------------------------------------------------
// QKV projection: Q = 1+elu(xWq+bq) [fp32], K0/V = bf16 (gathered later)
__global__ __launch_bounds__(256) void k_qkv(const void* __restrict__ x,
                                             const void* __restrict__ Wq, const void* __restrict__ bq,
                                             const void* __restrict__ Wk, const void* __restrict__ bk,
                                             const void* __restrict__ Wv, const void* __restrict__ bv,
                                             float* __restrict__ Q, unsigned short* __restrict__ K0b,
                                             unsigned short* __restrict__ Vb, const int* __restrict__ cnt) {
    __shared__ float sWq[64 * 64];
    __shared__ float sWk[64 * 64];
    __shared__ float sWv[64 * 64];
    __shared__ float sx[4][64];
    const bool bf = (cnt[0] < 16);
    const int t = threadIdx.x;
    for (int i = t; i < 4096; i += 256) {
        sWq[i] = ldf(Wq, i, bf);
        sWk[i] = ldf(Wk, i, bf);
        sWv[i] = ldf(Wv, i, bf);
    }
    __syncthreads();
    const int lane = t & 63, sub = t >> 6;
    const float bqv = ldf(bq, lane, bf), bkv = ldf(bk, lane, bf), bvv = ldf(bv, lane, bf);
    const int npb = (N_NODES + gridDim.x - 1) / gridDim.x;
    const int n0 = blockIdx.x * npb;
    const int n1 = min(n0 + npb, N_NODES);
    for (int nb = n0; nb < n1; nb += 4) {
        int n = nb + sub;
        __syncthreads();
        if (n < n1) sx[sub][lane] = ldf(x, n * 64 + lane, bf);
        __syncthreads();
        if (n < n1) {
            float q = bqv, k = bkv, v = bvv;
#pragma unroll 16
            for (int kk = 0; kk < 64; kk++) {
                float xv = sx[sub][kk];
                q += xv * sWq[kk * 64 + lane];
                k += xv * sWk[kk * 64 + lane];
                v += xv * sWv[kk * 64 + lane];
            }
            Q[n * 64 + lane]   = q > 0.0f ? q + 1.0f : __expf(q);
            K0b[n * 64 + lane] = f2us(k > 0.0f ? k + 1.0f : __expf(k));
            Vb[n * 64 + lane]  = f2us(v);
        }
    }
}

// ---------------------------------------------------------------------------
// Hop 1. Lane l = (h = l>>3, j = l&7). acc[i] = M1[n,h,i,j].
//   acc[i] += w * K0[src,h,i] * V[src,h,j]
// K0[h,0..7] direct-loaded as one uint4 (8 lanes share addr -> broadcast).
// Store transposed bf16: M1t[n][h][j][i] contiguous per lane (uint4).
__global__ __launch_bounds__(64) void k_hop1(const unsigned short* __restrict__ K0b,
                                             const unsigned short* __restrict__ Vb,
                                             const int* __restrict__ rowptr,
                                             const int* __restrict__ csr_src,
                                             const float* __restrict__ csr_w,
                                             unsigned short* __restrict__ M1b,
                                             unsigned short* __restrict__ K1b) {
    const int n = blockIdx.x;
    const int l = threadIdx.x;
    const int hb = l & 56;      // h*8
    const int j = l & 7;
    float acc[8] = {0, 0, 0, 0, 0, 0, 0, 0};
    float kacc = 0.0f;
    const int s0 = rowptr[n], s1 = rowptr[n + 1];
    for (int s = s0; s < s1; s++) {
        int src = csr_src[s];
        float w = csr_w[s];
        uint4 ku = *(const uint4*)(K0b + src * 64 + hb);
        float vown = us2f(Vb[src * 64 + l]);
        // own K0 element (h, j) extracted from ku
        unsigned int kw = ((const unsigned int*)&ku)[j >> 1];
        float kown = (j & 1) ? __uint_as_float(kw & 0xFFFF0000u) : __uint_as_float(kw << 16);
        float2 p0 = upk(ku.x), p1 = upk(ku.y), p2 = upk(ku.z), p3 = upk(ku.w);
        float wv = w * vown;
        acc[0] = fmaf(wv, p0.x, acc[0]); acc[1] = fmaf(wv, p0.y, acc[1]);
        acc[2] = fmaf(wv, p1.x, acc[2]); acc[3] = fmaf(wv, p1.y, acc[3]);
        acc[4] = fmaf(wv, p2.x, acc[4]); acc[5] = fmaf(wv, p2.y, acc[5]);
        acc[6] = fmaf(wv, p3.x, acc[6]); acc[7] = fmaf(wv, p3.y, acc[7]);
        kacc = fmaf(w, kown, kacc);
    }
    uint4 o;
    o.x = pk(acc[0], acc[1]); o.y = pk(acc[2], acc[3]);
    o.z = pk(acc[4], acc[5]); o.w = pk(acc[6], acc[7]);
    *(uint4*)(M1b + (size_t)n * 512 + l * 8) = o;
    K1b[n * 64 + l] = f2us(kacc);
}

// ---------------------------------------------------------------------------
// Hop 2 (fused, no M2). Lane l = (h, j'):
//   H2[n,h,j'] = sum_e w * sum_i Q[n,h,i] * M1t[src,h,j',i]   (per-lane scalar!)
//   C2[n,h]    = Q[n,h,:] . (sum_e w*K1[src,h,:]) + CST       (8-lane butterfly)
__global__ __launch_bounds__(64) void k_hop2(const float* __restrict__ Q,
                                             const unsigned short* __restrict__ M1b,
                                             const unsigned short* __restrict__ K1b,
                                             const int* __restrict__ rowptr,
                                             const int* __restrict__ csr_src,
                                             const float* __restrict__ csr_w,
                                             float* __restrict__ H2, float* __restrict__ C2) {
    const int n = blockIdx.x;
    const int l = threadIdx.x;
    const int hb = l & 56;
    float4 qa = *(const float4*)(Q + n * 64 + hb);
    float4 qb = *(const float4*)(Q + n * 64 + hb + 4);
    float qown = Q[n * 64 + l];
    float hacc = 0.0f, sk = 0.0f;
    const int s0 = rowptr[n], s1 = rowptr[n + 1];
    for (int s = s0; s < s1; s++) {
        int src = csr_src[s];
        float w = csr_w[s];
        uint4 mu = *(const uint4*)(M1b + (size_t)src * 512 + l * 8);
        float k1 = us2f(K1b[src * 64 + l]);
        float2 p0 = upk(mu.x), p1 = upk(mu.y), p2 = upk(mu.z), p3 = upk(mu.w);
        float d = qa.x * p0.x;
        d = fmaf(qa.y, p0.y, d); d = fmaf(qa.z, p1.x, d); d = fmaf(qa.w, p1.y, d);
        d = fmaf(qb.x, p2.x, d); d = fmaf(qb.y, p2.y, d);
        d = fmaf(qb.z, p3.x, d); d = fmaf(qb.w, p3.y, d);
        hacc = fmaf(w, d, hacc);
        sk = fmaf(w, k1, sk);
    }
    float cacc = qown * sk;
#pragma unroll
    for (int dd = 1; dd < 8; dd <<= 1) cacc += __shfl_xor(cacc, dd);
    H2[n * 64 + l] = hacc;
    if ((l & 7) == 0) C2[n * 8 + (l >> 3)] = cacc + CSTF;
}

// ---------------------------------------------------------------------------
// Finalize: H1 = Q.M1t[n] (per-lane), C1 butterfly; combine; out = hidden@Wo + bo
__global__ __launch_bounds__(64) void k_final(const float* __restrict__ Q,
                                              const unsigned short* __restrict__ M1b,
                                              const unsigned short* __restrict__ K1b,
                                              const unsigned short* __restrict__ Vb,
                                              const float* __restrict__ H2, const float* __restrict__ C2,
                                              const void* __restrict__ Wo, const void* __restrict__ bo,
                                              const void* __restrict__ hopwise,
                                              const void* __restrict__ headwise,
                                              void* __restrict__ out, const int* __restrict__ cnt) {
    const bool bf = (cnt[0] < 16);
    const int n = blockIdx.x;
    const int l = threadIdx.x;
    const int h = l >> 3, hb = l & 56;
    float4 qa = *(const float4*)(Q + n * 64 + hb);
    float4 qb = *(const float4*)(Q + n * 64 + hb + 4);
    float qown = Q[n * 64 + l];
    uint4 mu = *(const uint4*)(M1b + (size_t)n * 512 + l * 8);
    float2 p0 = upk(mu.x), p1 = upk(mu.y), p2 = upk(mu.z), p3 = upk(mu.w);
    float h1 = qa.x * p0.x;
    h1 = fmaf(qa.y, p0.y, h1); h1 = fmaf(qa.z, p1.x, h1); h1 = fmaf(qa.w, p1.y, h1);
    h1 = fmaf(qb.x, p2.x, h1); h1 = fmaf(qb.y, p2.y, h1);
    h1 = fmaf(qb.z, p3.x, h1); h1 = fmaf(qb.w, p3.y, h1);
    float c1 = qown * us2f(K1b[n * 64 + l]);
#pragma unroll
    for (int dd = 1; dd < 8; dd <<= 1) c1 += __shfl_xor(c1, dd);
    float h2 = H2[n * 64 + l];
    float c2 = C2[n * 8 + h];  // includes CST

    float hw0 = ldf(hopwise, 0, bf), hw1 = ldf(hopwise, 1, bf), hw2 = ldf(hopwise, 2, bf);
    float s0 = 0.0f, s1 = 0.0f;
#pragma unroll
    for (int hh = 0; hh < 8; hh++) {
        s0 += __expf(ldf(headwise, hh * 2 + 0, bf));
        s1 += __expf(ldf(headwise, hh * 2 + 1, bf));
    }
    float g1 = hw1 * __expf(ldf(headwise, h * 2 + 0, bf)) / s0;
    float g2 = hw2 * __expf(ldf(headwise, h * 2 + 1, bf)) / s1;

    float hidden = hw0 * us2f(Vb[n * 64 + l]) + g1 * h1 / (c1 + CSTF) + g2 * h2 / c2;

    // output projection: out[n,c] = sum_k hidden_k * Wo[k,c] + bo[c]; lane l = column c
    float o = ldf(bo, l, bf);
#pragma unroll 16
    for (int k = 0; k < 64; k++) {
        float hk = __shfl(hidden, k);
        o += hk * ldf(Wo, k * 64 + l, bf);
    }
    if (bf) ((bf16*)out)[n * 64 + l] = __float2bfloat16(o);
    else    ((float*)out)[n * 64 + l] = o;
}

// ---------------------------------------------------------------------------
extern "C" void kernel_launch(void* const* d_in, const int* in_sizes, int n_in,
                              void* d_out, int out_size, void* d_ws, size_t ws_size,
                              hipStream_t stream) {
    const void* x        = d_in[0];
    const void* ei       = d_in[1];
    const void* Wq       = d_in[3];
    const void* bq       = d_in[4];
    const void* Wk       = d_in[5];
    const void* bk       = d_in[6];
    const void* Wv       = d_in[7];
    const void* bv       = d_in[8];
    const void* Wo       = d_in[9];
    const void* bo       = d_in[10];
    const void* hopwise  = d_in[11];
    const void* headwise = d_in[12];

    char* p = (char*)d_ws;
    auto alloc = [&](size_t bytes) {
        void* r = (void*)p;
        p += (bytes + 255) & ~(size_t)255;
        return r;
    };
    float* Q            = (float*)alloc((size_t)N_NODES * 64 * 4);
    float* H2           = (float*)alloc((size_t)N_NODES * 64 * 4);
    float* C2           = (float*)alloc((size_t)N_NODES * 8 * 4);
    float* deg_inv      = (float*)alloc((size_t)N_NODES * 4);
    unsigned short* K0b = (unsigned short*)alloc((size_t)N_NODES * 64 * 2);
    unsigned short* Vb  = (unsigned short*)alloc((size_t)N_NODES * 64 * 2);
    unsigned short* K1b = (unsigned short*)alloc((size_t)N_NODES * 64 * 2);
    unsigned short* M1b = (unsigned short*)alloc((size_t)N_NODES * 512 * 2);
    float* csr_w        = (float*)alloc((size_t)N_EDGES * 4);
    int* csr_src        = (int*)alloc((size_t)N_EDGES * 4);
    int* deg            = (int*)alloc((size_t)N_NODES * 4);
    int* fill           = (int*)alloc((size_t)N_NODES * 4);
    int* rowptr         = (int*)alloc((size_t)(N_NODES + 1) * 4);
    int* cnt            = (int*)alloc(2 * 4);

    hipMemsetAsync(deg, 0, (size_t)N_NODES * 4, stream);
    hipMemsetAsync(fill, 0, (size_t)N_NODES * 4, stream);
    hipMemsetAsync(cnt, 0, 2 * 4, stream);

    const int EB = (N_EDGES + 255) / 256;
    const int NB = (N_NODES + 255) / 256;

    k_detect<<<256, 256, 0, stream>>>((const unsigned int*)x, (const unsigned int*)ei, cnt);
    k_deg<<<EB, 256, 0, stream>>>(ei, deg, cnt);
    k_deginv<<<NB, 256, 0, stream>>>(deg, deg_inv);
    k_scan<<<1, 1024, 0, stream>>>(deg, rowptr);
    k_fill<<<EB, 256, 0, stream>>>(ei, deg_inv, rowptr, fill, csr_src, csr_w, cnt);
    k_qkv<<<320, 256, 0, stream>>>(x, Wq, bq, Wk, bk, Wv, bv, Q, K0b, Vb, cnt);
    k_hop1<<<N_NODES, 64, 0, stream>>>(K0b, Vb, rowptr, csr_src, csr_w, M1b, K1b);
    k_hop2<<<N_NODES, 64, 0, stream>>>(Q, M1b, K1b, rowptr, csr_src, csr_w, H2, C2);
    k_final<<<N_NODES, 64, 0, stream>>>(Q, M1b, K1b, Vb, H2, C2, Wo, bo, hopwise, headwise, d_out, cnt);
}

// Round 4
// 315.007 us; speedup vs baseline: 1.3411x; 1.0751x over previous
//
#include <hip/hip_runtime.h>
#include <hip/hip_bf16.h>

typedef __hip_bfloat16 bf16;

#define N_NODES 20000
#define N_EDGES 320000
#define CSTF 1e-5f

__device__ __forceinline__ float us2f(unsigned short u) { return __uint_as_float(((unsigned int)u) << 16); }
__device__ __forceinline__ unsigned short f2us(float f) { return __bfloat16_as_ushort(__float2bfloat16(f)); }
__device__ __forceinline__ float2 upk(unsigned int u) {
    float2 r; r.x = __uint_as_float(u << 16); r.y = __uint_as_float(u & 0xFFFF0000u); return r;
}
__device__ __forceinline__ unsigned int pk(float a, float b) {
    return (unsigned int)f2us(a) | ((unsigned int)f2us(b) << 16);
}
__device__ __forceinline__ int rdl(int v, int lane) { return __builtin_amdgcn_readlane(v, lane); }
__device__ __forceinline__ float rdlf(float v, int lane) {
    return __int_as_float(__builtin_amdgcn_readlane(__float_as_int(v), lane));
}

// dtype-adaptive loads (flag is wave-uniform -> branch is free)
__device__ __forceinline__ float ldf(const void* p, int i, bool bf) {
    return bf ? __bfloat162float(((const bf16*)p)[i]) : ((const float*)p)[i];
}
__device__ __forceinline__ int ldi(const void* p, int i, bool w64) {
    return w64 ? (int)((const long long*)p)[i] : ((const int*)p)[i];
}

// ---------------------------------------------------------------------------
// Dtype detection: cnt[0] = #NaN-exponent ushorts in bf16-view of x
// (fp32 data -> thousands; real bf16 -> 0). cnt[1] = OR of odd uint32 words of
// edge_index (int64 -> 0; int32 -> nonzero).
__global__ void k_detect(const unsigned int* __restrict__ xs,
                         const unsigned int* __restrict__ eis,
                         int* __restrict__ cnt) {
    int t = blockIdx.x * blockDim.x + threadIdx.x;
    int nthr = gridDim.x * blockDim.x;
    int bad = 0;
    for (int i = t; i < N_NODES * 32; i += nthr) {
        unsigned int w = xs[i];
        if (((w >> 7)  & 0xFFu) == 0xFFu) bad++;
        if (((w >> 23) & 0xFFu) == 0xFFu) bad++;
    }
    unsigned int orv = 0;
    const uint2* e2 = (const uint2*)eis;
    for (int i = t; i < N_EDGES; i += nthr) orv |= e2[i].y;
    if (bad) atomicAdd(&cnt[0], bad);
    if (orv) atomicOr((unsigned int*)&cnt[1], orv);
}

// ---------------------------------------------------------------------------
__global__ void k_deg(const void* __restrict__ ei, int* __restrict__ deg,
                      const int* __restrict__ cnt) {
    bool i64 = (cnt[1] == 0);
    int e = blockIdx.x * blockDim.x + threadIdx.x;
    if (e < N_EDGES) atomicAdd(&deg[ldi(ei, N_EDGES + e, i64)], 1);
}

// Exclusive scan of deg -> rowptr + deg^-0.5 (single block)
__global__ __launch_bounds__(1024) void k_scan(const int* __restrict__ deg, int* __restrict__ rowptr,
                                               float* __restrict__ deg_inv) {
    __shared__ int part[1024];
    const int t = threadIdx.x;
    const int CH = (N_NODES + 1023) / 1024;  // 20
    int base = t * CH;
    int s = 0;
    for (int i = 0; i < CH; i++) {
        int idx = base + i;
        if (idx < N_NODES) {
            int d = deg[idx];
            s += d;
            deg_inv[idx] = d > 0 ? rsqrtf((float)d) : 0.0f;
        }
    }
    part[t] = s;
    __syncthreads();
    for (int off = 1; off < 1024; off <<= 1) {
        int v = (t >= off) ? part[t - off] : 0;
        __syncthreads();
        part[t] += v;
        __syncthreads();
    }
    int ex = (t == 0) ? 0 : part[t - 1];
    for (int i = 0; i < CH; i++) {
        int idx = base + i;
        if (idx < N_NODES) { rowptr[idx] = ex; ex += deg[idx]; }
    }
    if (t == 1023) rowptr[N_NODES] = part[1023];
}

__global__ void k_fill(const void* __restrict__ ei,
                       const float* __restrict__ deg_inv, const int* __restrict__ rowptr,
                       int* __restrict__ fill, int* __restrict__ csr_src, float* __restrict__ csr_w,
                       const int* __restrict__ cnt) {
    bool i64 = (cnt[1] == 0);
    int e = blockIdx.x * blockDim.x + threadIdx.x;
    if (e < N_EDGES) {
        int r = ldi(ei, e, i64);
        int c = ldi(ei, N_EDGES + e, i64);
        int slot = rowptr[c] + atomicAdd(&fill[c], 1);
        csr_src[slot] = r;
        csr_w[slot] = deg_inv[r] * deg_inv[c];
    }
}

// ---------------------------------------------------------------------------
// QKV projection: Q = 1+elu(xWq+bq) [fp32], K0/V = bf16 (gathered later)
__global__ __launch_bounds__(256) void k_qkv(const void* __restrict__ x,
                                             const void* __restrict__ Wq, const void* __restrict__ bq,
                                             const void* __restrict__ Wk, const void* __restrict__ bk,
                                             const void* __restrict__ Wv, const void* __restrict__ bv,
                                             float* __restrict__ Q, unsigned short* __restrict__ K0b,
                                             unsigned short* __restrict__ Vb, const int* __restrict__ cnt) {
    __shared__ float sWq[64 * 64];
    __shared__ float sWk[64 * 64];
    __shared__ float sWv[64 * 64];
    __shared__ float sx[4][64];
    const bool bf = (cnt[0] < 16);
    const int t = threadIdx.x;
    for (int i = t; i < 4096; i += 256) {
        sWq[i] = ldf(Wq, i, bf);
        sWk[i] = ldf(Wk, i, bf);
        sWv[i] = ldf(Wv, i, bf);
    }
    __syncthreads();
    const int lane = t & 63, sub = t >> 6;
    const float bqv = ldf(bq, lane, bf), bkv = ldf(bk, lane, bf), bvv = ldf(bv, lane, bf);
    const int npb = (N_NODES + gridDim.x - 1) / gridDim.x;
    const int n0 = blockIdx.x * npb;
    const int n1 = min(n0 + npb, N_NODES);
    for (int nb = n0; nb < n1; nb += 4) {
        int n = nb + sub;
        __syncthreads();
        if (n < n1) sx[sub][lane] = ldf(x, n * 64 + lane, bf);
        __syncthreads();
        if (n < n1) {
            float q = bqv, k = bkv, v = bvv;
#pragma unroll 16
            for (int kk = 0; kk < 64; kk++) {
                float xv = sx[sub][kk];
                q += xv * sWq[kk * 64 + lane];
                k += xv * sWk[kk * 64 + lane];
                v += xv * sWv[kk * 64 + lane];
            }
            Q[n * 64 + lane]   = q > 0.0f ? q + 1.0f : __expf(q);
            K0b[n * 64 + lane] = f2us(k > 0.0f ? k + 1.0f : __expf(k));
            Vb[n * 64 + lane]  = f2us(v);
        }
    }
}

// ---------------------------------------------------------------------------
// Hop 1. 4 waves/block, one node per wave. Lane l = (h = l>>3, j = l&7).
//   M1t[n][h][j][i] = sum_e w * K0[src,h,i] * V[src,h,j]  (acc[i], bf16 store)
// Edge indices prefetched per 64-chunk; readlane -> scalar per-edge src/w.
__global__ __launch_bounds__(256) void k_hop1(const unsigned short* __restrict__ K0b,
                                              const unsigned short* __restrict__ Vb,
                                              const int* __restrict__ rowptr,
                                              const int* __restrict__ csr_src,
                                              const float* __restrict__ csr_w,
                                              unsigned short* __restrict__ M1b,
                                              unsigned short* __restrict__ K1b) {
    const int l = threadIdx.x & 63;
    const int n = blockIdx.x * 4 + (threadIdx.x >> 6);
    const int hb = l & 56;
    float acc[8] = {0, 0, 0, 0, 0, 0, 0, 0};
    float kacc = 0.0f;
    const int s0 = rowptr[n], s1 = rowptr[n + 1];
    for (int c = s0; c < s1; c += 64) {
        const int m = min(64, s1 - c);
        const int idx = c + (l < m ? l : m - 1);
        const int srcv = csr_src[idx];
        const float wv = csr_w[idx];
#pragma unroll 4
        for (int e = 0; e < m; e++) {
            int src = rdl(srcv, e);
            float w = rdlf(wv, e);
            uint4 ku = *(const uint4*)(K0b + src * 64 + hb);
            float vown = us2f(Vb[src * 64 + l]);
            float kown = us2f(K0b[src * 64 + l]);
            float2 p0 = upk(ku.x), p1 = upk(ku.y), p2 = upk(ku.z), p3 = upk(ku.w);
            float wvv = w * vown;
            acc[0] = fmaf(wvv, p0.x, acc[0]); acc[1] = fmaf(wvv, p0.y, acc[1]);
            acc[2] = fmaf(wvv, p1.x, acc[2]); acc[3] = fmaf(wvv, p1.y, acc[3]);
            acc[4] = fmaf(wvv, p2.x, acc[4]); acc[5] = fmaf(wvv, p2.y, acc[5]);
            acc[6] = fmaf(wvv, p3.x, acc[6]); acc[7] = fmaf(wvv, p3.y, acc[7]);
            kacc = fmaf(w, kown, kacc);
        }
    }
    uint4 o;
    o.x = pk(acc[0], acc[1]); o.y = pk(acc[2], acc[3]);
    o.z = pk(acc[4], acc[5]); o.w = pk(acc[6], acc[7]);
    *(uint4*)(M1b + (size_t)n * 512 + l * 8) = o;
    K1b[n * 64 + l] = f2us(kacc);
}

// ---------------------------------------------------------------------------
// Hop 2 + finalize (fused). 4 waves/block, one node per wave. Lane l = (h, j').
//   H2[n,h,j'] = sum_e w * Q[n,h,:].M1t[src,h,j',:]   (per-lane scalar)
//   C2[n,h]    = Q[n,h,:].(sum_e w*K1[src,h,:]) + CST (8-lane butterfly)
// then H1/C1 from own row, gamma-combine, out = hidden@Wo + bo.
__global__ __launch_bounds__(256) void k_hop2f(const float* __restrict__ Q,
                                               const unsigned short* __restrict__ M1b,
                                               const unsigned short* __restrict__ K1b,
                                               const unsigned short* __restrict__ Vb,
                                               const int* __restrict__ rowptr,
                                               const int* __restrict__ csr_src,
                                               const float* __restrict__ csr_w,
                                               const void* __restrict__ Wo, const void* __restrict__ bo,
                                               const void* __restrict__ hopwise,
                                               const void* __restrict__ headwise,
                                               void* __restrict__ out, const int* __restrict__ cnt) {
    const bool bf = (cnt[0] < 16);
    const int l = threadIdx.x & 63;
    const int n = blockIdx.x * 4 + (threadIdx.x >> 6);
    const int hb = l & 56, h = l >> 3;
    const float4 qa = *(const float4*)(Q + n * 64 + hb);
    const float4 qb = *(const float4*)(Q + n * 64 + hb + 4);
    const float qown = Q[n * 64 + l];
    float hacc = 0.0f, sk = 0.0f;
    const int s0 = rowptr[n], s1 = rowptr[n + 1];
    for (int c = s0; c < s1; c += 64) {
        const int m = min(64, s1 - c);
        const int idx = c + (l < m ? l : m - 1);
        const int srcv = csr_src[idx];
        const float wv = csr_w[idx];
#pragma unroll 4
        for (int e = 0; e < m; e++) {
            int src = rdl(srcv, e);
            float w = rdlf(wv, e);
            uint4 mu = *(const uint4*)(M1b + (size_t)src * 512 + l * 8);
            float k1 = us2f(K1b[src * 64 + l]);
            float2 p0 = upk(mu.x), p1 = upk(mu.y), p2 = upk(mu.z), p3 = upk(mu.w);
            float d = qa.x * p0.x;
            d = fmaf(qa.y, p0.y, d); d = fmaf(qa.z, p1.x, d); d = fmaf(qa.w, p1.y, d);
            d = fmaf(qb.x, p2.x, d); d = fmaf(qb.y, p2.y, d);
            d = fmaf(qb.z, p3.x, d); d = fmaf(qb.w, p3.y, d);
            hacc = fmaf(w, d, hacc);
            sk = fmaf(w, k1, sk);
        }
    }
    // own-node H1 / C1
    uint4 mo = *(const uint4*)(M1b + (size_t)n * 512 + l * 8);
    float2 p0 = upk(mo.x), p1 = upk(mo.y), p2 = upk(mo.z), p3 = upk(mo.w);
    float h1 = qa.x * p0.x;
    h1 = fmaf(qa.y, p0.y, h1); h1 = fmaf(qa.z, p1.x, h1); h1 = fmaf(qa.w, p1.y, h1);
    h1 = fmaf(qb.x, p2.x, h1); h1 = fmaf(qb.y, p2.y, h1);
    h1 = fmaf(qb.z, p3.x, h1); h1 = fmaf(qb.w, p3.y, h1);
    float c1 = qown * us2f(K1b[n * 64 + l]);
    float c2 = qown * sk;
#pragma unroll
    for (int dd = 1; dd < 8; dd <<= 1) {
        c1 += __shfl_xor(c1, dd);
        c2 += __shfl_xor(c2, dd);
    }
    float hw0 = ldf(hopwise, 0, bf), hw1 = ldf(hopwise, 1, bf), hw2 = ldf(hopwise, 2, bf);
    float e0 = 0.0f, e1 = 0.0f;
#pragma unroll
    for (int hh = 0; hh < 8; hh++) {
        e0 += __expf(ldf(headwise, hh * 2 + 0, bf));
        e1 += __expf(ldf(headwise, hh * 2 + 1, bf));
    }
    float g1 = hw1 * __expf(ldf(headwise, h * 2 + 0, bf)) / e0;
    float g2 = hw2 * __expf(ldf(headwise, h * 2 + 1, bf)) / e1;

    float hidden = hw0 * us2f(Vb[n * 64 + l]) + g1 * h1 / (c1 + CSTF) + g2 * hacc / (c2 + CSTF);

    // output projection: out[n,c] = sum_k hidden_k * Wo[k,c] + bo[c]; lane l = column c
    float o = ldf(bo, l, bf);
#pragma unroll 16
    for (int k = 0; k < 64; k++) {
        float hk = __shfl(hidden, k);
        o += hk * ldf(Wo, k * 64 + l, bf);
    }
    if (bf) ((bf16*)out)[n * 64 + l] = __float2bfloat16(o);
    else    ((float*)out)[n * 64 + l] = o;
}

// ---------------------------------------------------------------------------
extern "C" void kernel_launch(void* const* d_in, const int* in_sizes, int n_in,
                              void* d_out, int out_size, void* d_ws, size_t ws_size,
                              hipStream_t stream) {
    const void* x        = d_in[0];
    const void* ei       = d_in[1];
    const void* Wq       = d_in[3];
    const void* bq       = d_in[4];
    const void* Wk       = d_in[5];
    const void* bk       = d_in[6];
    const void* Wv       = d_in[7];
    const void* bv       = d_in[8];
    const void* Wo       = d_in[9];
    const void* bo       = d_in[10];
    const void* hopwise  = d_in[11];
    const void* headwise = d_in[12];

    char* p = (char*)d_ws;
    auto alloc = [&](size_t bytes) {
        void* r = (void*)p;
        p += (bytes + 255) & ~(size_t)255;
        return r;
    };
    float* Q            = (float*)alloc((size_t)N_NODES * 64 * 4);
    float* deg_inv      = (float*)alloc((size_t)N_NODES * 4);
    unsigned short* K0b = (unsigned short*)alloc((size_t)N_NODES * 64 * 2);
    unsigned short* Vb  = (unsigned short*)alloc((size_t)N_NODES * 64 * 2);
    unsigned short* K1b = (unsigned short*)alloc((size_t)N_NODES * 64 * 2);
    unsigned short* M1b = (unsigned short*)alloc((size_t)N_NODES * 512 * 2);
    float* csr_w        = (float*)alloc((size_t)N_EDGES * 4);
    int* csr_src        = (int*)alloc((size_t)N_EDGES * 4);
    int* deg            = (int*)alloc((size_t)N_NODES * 4);
    int* fill           = (int*)alloc((size_t)N_NODES * 4);
    int* rowptr         = (int*)alloc((size_t)(N_NODES + 1) * 4);
    int* cnt            = (int*)alloc(2 * 4);

    hipMemsetAsync(deg, 0, (size_t)N_NODES * 4, stream);
    hipMemsetAsync(fill, 0, (size_t)N_NODES * 4, stream);
    hipMemsetAsync(cnt, 0, 2 * 4, stream);

    const int EB = (N_EDGES + 255) / 256;

    k_detect<<<256, 256, 0, stream>>>((const unsigned int*)x, (const unsigned int*)ei, cnt);
    k_deg<<<EB, 256, 0, stream>>>(ei, deg, cnt);
    k_scan<<<1, 1024, 0, stream>>>(deg, rowptr, deg_inv);
    k_fill<<<EB, 256, 0, stream>>>(ei, deg_inv, rowptr, fill, csr_src, csr_w, cnt);
    k_qkv<<<625, 256, 0, stream>>>(x, Wq, bq, Wk, bk, Wv, bv, Q, K0b, Vb, cnt);
    k_hop1<<<N_NODES / 4, 256, 0, stream>>>(K0b, Vb, rowptr, csr_src, csr_w, M1b, K1b);
    k_hop2f<<<N_NODES / 4, 256, 0, stream>>>(Q, M1b, K1b, Vb, rowptr, csr_src, csr_w,
                                             Wo, bo, hopwise, headwise, d_out, cnt);
}

// Round 7
// 296.797 us; speedup vs baseline: 1.4234x; 1.0614x over previous
//
#include <hip/hip_runtime.h>
#include <hip/hip_bf16.h>

typedef __hip_bfloat16 bf16;
typedef __fp16 half2_t __attribute__((ext_vector_type(2)));

#define N_NODES 20000
#define N_EDGES 320000
#define CSTF 1e-5f

__device__ __forceinline__ half2_t u2h(unsigned int u) {
    union { unsigned int u; half2_t h; } c; c.u = u; return c.h;
}
// RNE pack of two floats to packed f16 (plain casts -> v_cvt_f16_f32, RNE)
__device__ __forceinline__ unsigned int pkh(float a, float b) {
    union { __fp16 h[2]; unsigned int u; } c;
    c.h[0] = (__fp16)a; c.h[1] = (__fp16)b;
    return c.u;
}
__device__ __forceinline__ half2_t mkh2(float a, float b) {
    half2_t h; h.x = (__fp16)a; h.y = (__fp16)b; return h;
}
#if defined(__has_builtin)
#if __has_builtin(__builtin_amdgcn_fdot2)
#define HAVE_FDOT2 1
#endif
#endif
__device__ __forceinline__ float fdot2(half2_t a, half2_t b, float c) {
#ifdef HAVE_FDOT2
    return __builtin_amdgcn_fdot2(a, b, c, false);
#else
    return fmaf((float)a.x, (float)b.x, fmaf((float)a.y, (float)b.y, c));
#endif
}
__device__ __forceinline__ int rdl(int v, int lane) { return __builtin_amdgcn_readlane(v, lane); }
__device__ __forceinline__ float rdlf(float v, int lane) {
    return __int_as_float(__builtin_amdgcn_readlane(__float_as_int(v), lane));
}

// dtype-adaptive loads (flag is wave-uniform -> branch is free)
__device__ __forceinline__ float ldf(const void* p, int i, bool bf) {
    return bf ? __bfloat162float(((const bf16*)p)[i]) : ((const float*)p)[i];
}
__device__ __forceinline__ int ldi(const void* p, int i, bool w64) {
    return w64 ? (int)((const long long*)p)[i] : ((const int*)p)[i];
}

// ---------------------------------------------------------------------------
// Dtype detection (sampled): cnt[0] = #NaN-exponent ushorts in bf16-view of x
// (fp32 data -> ~300 hits in sample; real bf16 -> 0). cnt[1] = OR of odd
// uint32 words of edge_index head (int64 -> 0; int32 -> nonzero).
__global__ void k_detect(const unsigned int* __restrict__ xs,
                         const unsigned int* __restrict__ eis,
                         int* __restrict__ cnt) {
    int t = blockIdx.x * blockDim.x + threadIdx.x;
    int nthr = gridDim.x * blockDim.x;
    int bad = 0;
    for (int i = t; i < 40000; i += nthr) {
        unsigned int w = xs[i];
        if (((w >> 7)  & 0xFFu) == 0xFFu) bad++;
        if (((w >> 23) & 0xFFu) == 0xFFu) bad++;
    }
    unsigned int orv = 0;
    const uint2* e2 = (const uint2*)eis;
    for (int i = t; i < 32768; i += nthr) orv |= e2[i].y;
    if (bad) atomicAdd(&cnt[0], bad);
    if (orv) atomicOr((unsigned int*)&cnt[1], orv);
}

// ---------------------------------------------------------------------------
__global__ void k_deg(const void* __restrict__ ei, int* __restrict__ deg,
                      const int* __restrict__ cnt) {
    bool i64 = (cnt[1] == 0);
    int e = blockIdx.x * blockDim.x + threadIdx.x;
    if (e < N_EDGES) atomicAdd(&deg[ldi(ei, N_EDGES + e, i64)], 1);
}

// Exclusive scan of deg -> rowptr + deg^-0.5 (single block)
__global__ __launch_bounds__(1024) void k_scan(const int* __restrict__ deg, int* __restrict__ rowptr,
                                               float* __restrict__ deg_inv) {
    __shared__ int part[1024];
    const int t = threadIdx.x;
    const int CH = (N_NODES + 1023) / 1024;  // 20
    int base = t * CH;
    int s = 0;
    for (int i = 0; i < CH; i++) {
        int idx = base + i;
        if (idx < N_NODES) {
            int d = deg[idx];
            s += d;
            deg_inv[idx] = d > 0 ? rsqrtf((float)d) : 0.0f;
        }
    }
    part[t] = s;
    __syncthreads();
    for (int off = 1; off < 1024; off <<= 1) {
        int v = (t >= off) ? part[t - off] : 0;
        __syncthreads();
        part[t] += v;
        __syncthreads();
    }
    int ex = (t == 0) ? 0 : part[t - 1];
    for (int i = 0; i < CH; i++) {
        int idx = base + i;
        if (idx < N_NODES) { rowptr[idx] = ex; ex += deg[idx]; }
    }
    if (t == 1023) rowptr[N_NODES] = part[1023];
}

__global__ void k_fill(const void* __restrict__ ei,
                       const float* __restrict__ deg_inv, const int* __restrict__ rowptr,
                       int* __restrict__ fill, int* __restrict__ csr_src, float* __restrict__ csr_w,
                       const int* __restrict__ cnt) {
    bool i64 = (cnt[1] == 0);
    int e = blockIdx.x * blockDim.x + threadIdx.x;
    if (e < N_EDGES) {
        int r = ldi(ei, e, i64);
        int c = ldi(ei, N_EDGES + e, i64);
        int slot = rowptr[c] + atomicAdd(&fill[c], 1);
        csr_src[slot] = r;
        csr_w[slot] = deg_inv[r] * deg_inv[c];
    }
}

// ---------------------------------------------------------------------------
// QKV projection: Q = 1+elu(xWq+bq) [fp32], K0/V staged as f16
__global__ __launch_bounds__(256) void k_qkv(const void* __restrict__ x,
                                             const void* __restrict__ Wq, const void* __restrict__ bq,
                                             const void* __restrict__ Wk, const void* __restrict__ bk,
                                             const void* __restrict__ Wv, const void* __restrict__ bv,
                                             float* __restrict__ Q, _Float16* __restrict__ K0h,
                                             _Float16* __restrict__ Vh, const int* __restrict__ cnt) {
    __shared__ float sWq[64 * 64];
    __shared__ float sWk[64 * 64];
    __shared__ float sWv[64 * 64];
    __shared__ float sx[4][64];
    const bool bf = (cnt[0] < 16);
    const int t = threadIdx.x;
    for (int i = t; i < 4096; i += 256) {
        sWq[i] = ldf(Wq, i, bf);
        sWk[i] = ldf(Wk, i, bf);
        sWv[i] = ldf(Wv, i, bf);
    }
    __syncthreads();
    const int lane = t & 63, sub = t >> 6;
    const float bqv = ldf(bq, lane, bf), bkv = ldf(bk, lane, bf), bvv = ldf(bv, lane, bf);
    const int npb = (N_NODES + gridDim.x - 1) / gridDim.x;
    const int n0 = blockIdx.x * npb;
    const int n1 = min(n0 + npb, N_NODES);
    for (int nb = n0; nb < n1; nb += 4) {
        int n = nb + sub;
        __syncthreads();
        if (n < n1) sx[sub][lane] = ldf(x, n * 64 + lane, bf);
        __syncthreads();
        if (n < n1) {
            float q = bqv, k = bkv, v = bvv;
#pragma unroll 16
            for (int kk = 0; kk < 64; kk++) {
                float xv = sx[sub][kk];
                q += xv * sWq[kk * 64 + lane];
                k += xv * sWk[kk * 64 + lane];
                v += xv * sWv[kk * 64 + lane];
            }
            Q[n * 64 + lane]   = q > 0.0f ? q + 1.0f : __expf(q);
            K0h[n * 64 + lane] = (_Float16)(k > 0.0f ? k + 1.0f : __expf(k));
            Vh[n * 64 + lane]  = (_Float16)v;
        }
    }
}

// ---------------------------------------------------------------------------
// Hop 1. 128-thr blocks, one node per wave. Lane l = (h = l>>3, j = l&7).
//   M1t[n][h][j][i] = sum_e w * K0[src,h,i] * V[src,h,j]  (acc fp32, f16 store)
// M1 layout (uints): node stride 256, lane offset l*4 (16 B per lane).
__global__ __launch_bounds__(128) void k_hop1(const _Float16* __restrict__ K0h,
                                              const _Float16* __restrict__ Vh,
                                              const int* __restrict__ rowptr,
                                              const int* __restrict__ csr_src,
                                              const float* __restrict__ csr_w,
                                              unsigned int* __restrict__ M1h,  // uint for vec io
                                              _Float16* __restrict__ K1h) {
    const int l = threadIdx.x & 63;
    const int n = blockIdx.x * 2 + (threadIdx.x >> 6);
    const int hb = l & 56;
    float acc[8] = {0, 0, 0, 0, 0, 0, 0, 0};
    float kacc = 0.0f;
    const int s0 = rowptr[n], s1 = rowptr[n + 1];
    for (int c = s0; c < s1; c += 64) {
        const int m = min(64, s1 - c);
        const int idx = c + (l < m ? l : m - 1);
        const int srcv = csr_src[idx];
        const float wv = csr_w[idx];
#pragma unroll 8
        for (int e = 0; e < m; e++) {
            int src = rdl(srcv, e);
            float w = rdlf(wv, e);
            uint4 ku = *(const uint4*)(K0h + src * 64 + hb);   // 8 f16 = 16B
            float vown = (float)Vh[src * 64 + l];
            float kown = (float)K0h[src * 64 + l];
            half2_t p0 = u2h(ku.x), p1 = u2h(ku.y), p2 = u2h(ku.z), p3 = u2h(ku.w);
            float wvv = w * vown;
            acc[0] = fmaf(wvv, (float)p0.x, acc[0]); acc[1] = fmaf(wvv, (float)p0.y, acc[1]);
            acc[2] = fmaf(wvv, (float)p1.x, acc[2]); acc[3] = fmaf(wvv, (float)p1.y, acc[3]);
            acc[4] = fmaf(wvv, (float)p2.x, acc[4]); acc[5] = fmaf(wvv, (float)p2.y, acc[5]);
            acc[6] = fmaf(wvv, (float)p3.x, acc[6]); acc[7] = fmaf(wvv, (float)p3.y, acc[7]);
            kacc = fmaf(w, kown, kacc);
        }
    }
    uint4 o;
    o.x = pkh(acc[0], acc[1]); o.y = pkh(acc[2], acc[3]);
    o.z = pkh(acc[4], acc[5]); o.w = pkh(acc[6], acc[7]);
    *(uint4*)(M1h + (size_t)n * 256 + l * 4) = o;
    K1h[n * 64 + l] = (_Float16)kacc;
}

// ---------------------------------------------------------------------------
// Hop 2 + finalize (fused). 128-thr blocks, one node per wave. Lane l = (h, j').
//   H2[n,h,j'] = sum_e w * Q[n,h,:].M1t[src,h,j',:]   (4x fdot2 per edge)
//   C2[n,h]    = Q[n,h,:].(sum_e w*K1[src,h,:]) + CST (8-lane butterfly)
// then H1/C1 from own row, gamma-combine, out = hidden@Wo + bo.
__global__ __launch_bounds__(128) void k_hop2f(const float* __restrict__ Q,
                                               const unsigned int* __restrict__ M1h,
                                               const _Float16* __restrict__ K1h,
                                               const _Float16* __restrict__ Vh,
                                               const int* __restrict__ rowptr,
                                               const int* __restrict__ csr_src,
                                               const float* __restrict__ csr_w,
                                               const void* __restrict__ Wo, const void* __restrict__ bo,
                                               const void* __restrict__ hopwise,
                                               const void* __restrict__ headwise,
                                               void* __restrict__ out, const int* __restrict__ cnt) {
    const bool bf = (cnt[0] < 16);
    const int l = threadIdx.x & 63;
    const int n = blockIdx.x * 2 + (threadIdx.x >> 6);
    const int hb = l & 56, h = l >> 3;
    const float4 qa = *(const float4*)(Q + n * 64 + hb);
    const float4 qb = *(const float4*)(Q + n * 64 + hb + 4);
    const float qown = Q[n * 64 + l];
    const half2_t q01 = mkh2(qa.x, qa.y);
    const half2_t q23 = mkh2(qa.z, qa.w);
    const half2_t q45 = mkh2(qb.x, qb.y);
    const half2_t q67 = mkh2(qb.z, qb.w);
    float hacc = 0.0f, sk = 0.0f;
    const int s0 = rowptr[n], s1 = rowptr[n + 1];
    for (int c = s0; c < s1; c += 64) {
        const int m = min(64, s1 - c);
        const int idx = c + (l < m ? l : m - 1);
        const int srcv = csr_src[idx];
        const float wv = csr_w[idx];
#pragma unroll 8
        for (int e = 0; e < m; e++) {
            int src = rdl(srcv, e);
            float w = rdlf(wv, e);
            uint4 mu = *(const uint4*)(M1h + (size_t)src * 256 + l * 4);
            float k1 = (float)K1h[src * 64 + l];
            float d = fdot2(q01, u2h(mu.x), 0.0f);
            d = fdot2(q23, u2h(mu.y), d);
            d = fdot2(q45, u2h(mu.z), d);
            d = fdot2(q67, u2h(mu.w), d);
            hacc = fmaf(w, d, hacc);
            sk = fmaf(w, k1, sk);
        }
    }
    // own-node H1 / C1
    uint4 mo = *(const uint4*)(M1h + (size_t)n * 256 + l * 4);
    float h1 = fdot2(q01, u2h(mo.x), 0.0f);
    h1 = fdot2(q23, u2h(mo.y), h1);
    h1 = fdot2(q45, u2h(mo.z), h1);
    h1 = fdot2(q67, u2h(mo.w), h1);
    float c1 = qown * (float)K1h[n * 64 + l];
    float c2 = qown * sk;
#pragma unroll
    for (int dd = 1; dd < 8; dd <<= 1) {
        c1 += __shfl_xor(c1, dd);
        c2 += __shfl_xor(c2, dd);
    }
    float hw0 = ldf(hopwise, 0, bf), hw1 = ldf(hopwise, 1, bf), hw2 = ldf(hopwise, 2, bf);
    float e0 = 0.0f, e1 = 0.0f;
#pragma unroll
    for (int hh = 0; hh < 8; hh++) {
        e0 += __expf(ldf(headwise, hh * 2 + 0, bf));
        e1 += __expf(ldf(headwise, hh * 2 + 1, bf));
    }
    float g1 = hw1 * __expf(ldf(headwise, h * 2 + 0, bf)) / e0;
    float g2 = hw2 * __expf(ldf(headwise, h * 2 + 1, bf)) / e1;

    float hidden = hw0 * (float)Vh[n * 64 + l] + g1 * h1 / (c1 + CSTF) + g2 * hacc / (c2 + CSTF);

    // output projection: out[n,c] = sum_k hidden_k * Wo[k,c] + bo[c]; lane l = column c
    float o = ldf(bo, l, bf);
#pragma unroll 16
    for (int k = 0; k < 64; k++) {
        float hk = __shfl(hidden, k);
        o += hk * ldf(Wo, k * 64 + l, bf);
    }
    if (bf) ((bf16*)out)[n * 64 + l] = __float2bfloat16(o);
    else    ((float*)out)[n * 64 + l] = o;
}

// ---------------------------------------------------------------------------
extern "C" void kernel_launch(void* const* d_in, const int* in_sizes, int n_in,
                              void* d_out, int out_size, void* d_ws, size_t ws_size,
                              hipStream_t stream) {
    const void* x        = d_in[0];
    const void* ei       = d_in[1];
    const void* Wq       = d_in[3];
    const void* bq       = d_in[4];
    const void* Wk       = d_in[5];
    const void* bk       = d_in[6];
    const void* Wv       = d_in[7];
    const void* bv       = d_in[8];
    const void* Wo       = d_in[9];
    const void* bo       = d_in[10];
    const void* hopwise  = d_in[11];
    const void* headwise = d_in[12];

    char* p = (char*)d_ws;
    auto alloc = [&](size_t bytes) {
        void* r = (void*)p;
        p += (bytes + 255) & ~(size_t)255;
        return r;
    };
    float* Q          = (float*)alloc((size_t)N_NODES * 64 * 4);
    float* deg_inv    = (float*)alloc((size_t)N_NODES * 4);
    _Float16* K0h     = (_Float16*)alloc((size_t)N_NODES * 64 * 2);
    _Float16* Vh      = (_Float16*)alloc((size_t)N_NODES * 64 * 2);
    _Float16* K1h     = (_Float16*)alloc((size_t)N_NODES * 64 * 2);
    unsigned int* M1h = (unsigned int*)alloc((size_t)N_NODES * 512 * 2);
    float* csr_w      = (float*)alloc((size_t)N_EDGES * 4);
    int* csr_src      = (int*)alloc((size_t)N_EDGES * 4);
    int* deg          = (int*)alloc((size_t)N_NODES * 4);
    int* fill         = (int*)alloc((size_t)N_NODES * 4);
    int* rowptr       = (int*)alloc((size_t)(N_NODES + 1) * 4);
    int* cnt          = (int*)alloc(2 * 4);

    (void)hipMemsetAsync(deg, 0, (size_t)N_NODES * 4, stream);
    (void)hipMemsetAsync(fill, 0, (size_t)N_NODES * 4, stream);
    (void)hipMemsetAsync(cnt, 0, 2 * 4, stream);

    const int EB = (N_EDGES + 255) / 256;

    k_detect<<<64, 256, 0, stream>>>((const unsigned int*)x, (const unsigned int*)ei, cnt);
    k_deg<<<EB, 256, 0, stream>>>(ei, deg, cnt);
    k_scan<<<1, 1024, 0, stream>>>(deg, rowptr, deg_inv);
    k_fill<<<EB, 256, 0, stream>>>(ei, deg_inv, rowptr, fill, csr_src, csr_w, cnt);
    k_qkv<<<625, 256, 0, stream>>>(x, Wq, bq, Wk, bk, Wv, bv, Q, K0h, Vh, cnt);
    k_hop1<<<N_NODES / 2, 128, 0, stream>>>(K0h, Vh, rowptr, csr_src, csr_w, M1h, K1h);
    k_hop2f<<<N_NODES / 2, 128, 0, stream>>>(Q, M1h, K1h, Vh, rowptr, csr_src, csr_w,
                                             Wo, bo, hopwise, headwise, d_out, cnt);
}

// Round 8
// 269.996 us; speedup vs baseline: 1.5647x; 1.0993x over previous
//
#include <hip/hip_runtime.h>
#include <hip/hip_bf16.h>

typedef __hip_bfloat16 bf16;
typedef __fp16 half2_t __attribute__((ext_vector_type(2)));

#define N_NODES 20000
#define N_EDGES 320000
#define CSTF 1e-5f

__device__ __forceinline__ half2_t u2h(unsigned int u) {
    union { unsigned int u; half2_t h; } c; c.u = u; return c.h;
}
__device__ __forceinline__ unsigned int pkh(float a, float b) {
    union { __fp16 h[2]; unsigned int u; } c;
    c.h[0] = (__fp16)a; c.h[1] = (__fp16)b;
    return c.u;
}
__device__ __forceinline__ half2_t mkh2(float a, float b) {
    half2_t h; h.x = (__fp16)a; h.y = (__fp16)b; return h;
}
#if defined(__has_builtin)
#if __has_builtin(__builtin_amdgcn_fdot2)
#define HAVE_FDOT2 1
#endif
#endif
__device__ __forceinline__ float fdot2(half2_t a, half2_t b, float c) {
#ifdef HAVE_FDOT2
    return __builtin_amdgcn_fdot2(a, b, c, false);
#else
    return fmaf((float)a.x, (float)b.x, fmaf((float)a.y, (float)b.y, c));
#endif
}
__device__ __forceinline__ int rdl(int v, int lane) { return __builtin_amdgcn_readlane(v, lane); }
__device__ __forceinline__ float rdlf(float v, int lane) {
    return __int_as_float(__builtin_amdgcn_readlane(__float_as_int(v), lane));
}

__device__ __forceinline__ float ldf(const void* p, int i, bool bf) {
    return bf ? __bfloat162float(((const bf16*)p)[i]) : ((const float*)p)[i];
}
__device__ __forceinline__ int ldi(const void* p, int i, bool w64) {
    return w64 ? (int)((const long long*)p)[i] : ((const int*)p)[i];
}

// Per-wave int64-vs-int32 self-detection for edge e (full wave active).
// Word 2e+1 is: int64 -> hi-word of row[e] (always 0 for values < 2^31);
// int32 -> some other edge value (nonzero w.p. 1-1/20000 per lane).
// In-bounds for both layouts (2e+1 < 640000 words = int32 buffer size).
__device__ __forceinline__ bool wave_is_i64(const void* ei, int e) {
    unsigned int hi = ((const unsigned int*)ei)[2 * e + 1];
    return !__any(hi != 0);
}

// ---------------------------------------------------------------------------
// Phase 1: in-degree count over col (per-wave i64 detect) + sampled x-dtype
// detection (cnt[0] = #NaN-exponent ushorts in bf16-view; fp32 -> ~300, bf16 -> 0)
__global__ __launch_bounds__(256) void k_p1(const unsigned int* __restrict__ xs,
                                            const void* __restrict__ ei,
                                            int* __restrict__ deg, int* __restrict__ cnt) {
    const int e = blockIdx.x * 256 + threadIdx.x;
    bool i64 = wave_is_i64(ei, e);
    int c = i64 ? (int)((const long long*)ei)[N_EDGES + e] : ((const int*)ei)[N_EDGES + e];
    atomicAdd(&deg[c], 1);
    if (blockIdx.x < 64) {
        int t = blockIdx.x * 256 + threadIdx.x;
        int bad = 0;
        for (int i = t; i < 40000; i += 64 * 256) {
            unsigned int w = xs[i];
            if (((w >> 7)  & 0xFFu) == 0xFFu) bad++;
            if (((w >> 23) & 0xFFu) == 0xFFu) bad++;
        }
        if (bad) atomicAdd(&cnt[0], bad);
    }
}

// Exclusive scan of deg -> rowptr + deg^-0.5 (single block)
__global__ __launch_bounds__(1024) void k_scan(const int* __restrict__ deg, int* __restrict__ rowptr,
                                               float* __restrict__ deg_inv) {
    __shared__ int part[1024];
    const int t = threadIdx.x;
    const int CH = (N_NODES + 1023) / 1024;  // 20
    int base = t * CH;
    int s = 0;
    for (int i = 0; i < CH; i++) {
        int idx = base + i;
        if (idx < N_NODES) {
            int d = deg[idx];
            s += d;
            deg_inv[idx] = d > 0 ? rsqrtf((float)d) : 0.0f;
        }
    }
    part[t] = s;
    __syncthreads();
    for (int off = 1; off < 1024; off <<= 1) {
        int v = (t >= off) ? part[t - off] : 0;
        __syncthreads();
        part[t] += v;
        __syncthreads();
    }
    int ex = (t == 0) ? 0 : part[t - 1];
    for (int i = 0; i < CH; i++) {
        int idx = base + i;
        if (idx < N_NODES) { rowptr[idx] = ex; ex += deg[idx]; }
    }
    if (t == 1023) rowptr[N_NODES] = part[1023];
}

// ---------------------------------------------------------------------------
// Phase 2 (fused independent work):
//   blocks [0,625):    QKV projection  (Q fp32; K0,V staged f16)
//   blocks [625,1875): CSR fill (per-wave i64 detect)
#define QKV_BLOCKS 625
__global__ __launch_bounds__(256) void k_p2(const void* __restrict__ x,
                                            const void* __restrict__ Wq, const void* __restrict__ bq,
                                            const void* __restrict__ Wk, const void* __restrict__ bk,
                                            const void* __restrict__ Wv, const void* __restrict__ bv,
                                            float* __restrict__ Q, _Float16* __restrict__ K0h,
                                            _Float16* __restrict__ Vh,
                                            const void* __restrict__ ei,
                                            const float* __restrict__ deg_inv,
                                            const int* __restrict__ rowptr,
                                            int* __restrict__ fill, int* __restrict__ csr_src,
                                            float* __restrict__ csr_w,
                                            const int* __restrict__ cnt) {
    __shared__ float sWq[64 * 64];
    __shared__ float sWk[64 * 64];
    __shared__ float sWv[64 * 64];
    __shared__ float sx[4][64];
    const int t = threadIdx.x;
    if (blockIdx.x >= QKV_BLOCKS) {
        // ---- CSR fill ----
        const int e = (blockIdx.x - QKV_BLOCKS) * 256 + t;
        bool i64 = wave_is_i64(ei, e);
        int r, c;
        if (i64) {
            r = (int)((const long long*)ei)[e];
            c = (int)((const long long*)ei)[N_EDGES + e];
        } else {
            r = ((const int*)ei)[e];
            c = ((const int*)ei)[N_EDGES + e];
        }
        int slot = rowptr[c] + atomicAdd(&fill[c], 1);
        csr_src[slot] = r;
        csr_w[slot] = deg_inv[r] * deg_inv[c];
        return;
    }
    // ---- QKV ----
    const bool bf = (cnt[0] < 16);
    for (int i = t; i < 4096; i += 256) {
        sWq[i] = ldf(Wq, i, bf);
        sWk[i] = ldf(Wk, i, bf);
        sWv[i] = ldf(Wv, i, bf);
    }
    __syncthreads();
    const int lane = t & 63, sub = t >> 6;
    const float bqv = ldf(bq, lane, bf), bkv = ldf(bk, lane, bf), bvv = ldf(bv, lane, bf);
    const int npb = (N_NODES + QKV_BLOCKS - 1) / QKV_BLOCKS;  // 32
    const int n0 = blockIdx.x * npb;
    const int n1 = min(n0 + npb, N_NODES);
    for (int nb = n0; nb < n1; nb += 4) {
        int n = nb + sub;
        __syncthreads();
        if (n < n1) sx[sub][lane] = ldf(x, n * 64 + lane, bf);
        __syncthreads();
        if (n < n1) {
            float q = bqv, k = bkv, v = bvv;
#pragma unroll 16
            for (int kk = 0; kk < 64; kk++) {
                float xv = sx[sub][kk];
                q += xv * sWq[kk * 64 + lane];
                k += xv * sWk[kk * 64 + lane];
                v += xv * sWv[kk * 64 + lane];
            }
            Q[n * 64 + lane]   = q > 0.0f ? q + 1.0f : __expf(q);
            K0h[n * 64 + lane] = (_Float16)(k > 0.0f ? k + 1.0f : __expf(k));
            Vh[n * 64 + lane]  = (_Float16)v;
        }
    }
}

// ---------------------------------------------------------------------------
// Hop 1. 128-thr blocks, one node per wave. Lane l = (h = l>>3, j = l&7).
//   M1t[n][h][j][i] = sum_e w * K0[src,h,i] * V[src,h,j]  (acc fp32, f16 store)
__global__ __launch_bounds__(128) void k_hop1(const _Float16* __restrict__ K0h,
                                              const _Float16* __restrict__ Vh,
                                              const int* __restrict__ rowptr,
                                              const int* __restrict__ csr_src,
                                              const float* __restrict__ csr_w,
                                              unsigned int* __restrict__ M1h,
                                              _Float16* __restrict__ K1h) {
    const int l = threadIdx.x & 63;
    const int n = blockIdx.x * 2 + (threadIdx.x >> 6);
    const int hb = l & 56;
    float acc[8] = {0, 0, 0, 0, 0, 0, 0, 0};
    float kacc = 0.0f;
    const int s0 = rowptr[n], s1 = rowptr[n + 1];
    for (int c = s0; c < s1; c += 64) {
        const int m = min(64, s1 - c);
        const int idx = c + (l < m ? l : m - 1);
        const int srcv = csr_src[idx];
        const float wv = csr_w[idx];
#pragma unroll 8
        for (int e = 0; e < m; e++) {
            int src = rdl(srcv, e);
            float w = rdlf(wv, e);
            uint4 ku = *(const uint4*)(K0h + src * 64 + hb);
            float vown = (float)Vh[src * 64 + l];
            float kown = (float)K0h[src * 64 + l];
            half2_t p0 = u2h(ku.x), p1 = u2h(ku.y), p2 = u2h(ku.z), p3 = u2h(ku.w);
            float wvv = w * vown;
            acc[0] = fmaf(wvv, (float)p0.x, acc[0]); acc[1] = fmaf(wvv, (float)p0.y, acc[1]);
            acc[2] = fmaf(wvv, (float)p1.x, acc[2]); acc[3] = fmaf(wvv, (float)p1.y, acc[3]);
            acc[4] = fmaf(wvv, (float)p2.x, acc[4]); acc[5] = fmaf(wvv, (float)p2.y, acc[5]);
            acc[6] = fmaf(wvv, (float)p3.x, acc[6]); acc[7] = fmaf(wvv, (float)p3.y, acc[7]);
            kacc = fmaf(w, kown, kacc);
        }
    }
    uint4 o;
    o.x = pkh(acc[0], acc[1]); o.y = pkh(acc[2], acc[3]);
    o.z = pkh(acc[4], acc[5]); o.w = pkh(acc[6], acc[7]);
    *(uint4*)(M1h + (size_t)n * 256 + l * 4) = o;
    K1h[n * 64 + l] = (_Float16)kacc;
}

// ---------------------------------------------------------------------------
// Hop 2 + finalize (fused). 128-thr blocks, one node per wave. Lane l = (h, j').
__global__ __launch_bounds__(128) void k_hop2f(const float* __restrict__ Q,
                                               const unsigned int* __restrict__ M1h,
                                               const _Float16* __restrict__ K1h,
                                               const _Float16* __restrict__ Vh,
                                               const int* __restrict__ rowptr,
                                               const int* __restrict__ csr_src,
                                               const float* __restrict__ csr_w,
                                               const void* __restrict__ Wo, const void* __restrict__ bo,
                                               const void* __restrict__ hopwise,
                                               const void* __restrict__ headwise,
                                               void* __restrict__ out, const int* __restrict__ cnt) {
    const bool bf = (cnt[0] < 16);
    const int l = threadIdx.x & 63;
    const int n = blockIdx.x * 2 + (threadIdx.x >> 6);
    const int hb = l & 56, h = l >> 3;
    const float4 qa = *(const float4*)(Q + n * 64 + hb);
    const float4 qb = *(const float4*)(Q + n * 64 + hb + 4);
    const float qown = Q[n * 64 + l];
    const half2_t q01 = mkh2(qa.x, qa.y);
    const half2_t q23 = mkh2(qa.z, qa.w);
    const half2_t q45 = mkh2(qb.x, qb.y);
    const half2_t q67 = mkh2(qb.z, qb.w);
    float hacc = 0.0f, sk = 0.0f;
    const int s0 = rowptr[n], s1 = rowptr[n + 1];
    for (int c = s0; c < s1; c += 64) {
        const int m = min(64, s1 - c);
        const int idx = c + (l < m ? l : m - 1);
        const int srcv = csr_src[idx];
        const float wv = csr_w[idx];
#pragma unroll 16
        for (int e = 0; e < m; e++) {
            int src = rdl(srcv, e);
            float w = rdlf(wv, e);
            uint4 mu = *(const uint4*)(M1h + (size_t)src * 256 + l * 4);
            float k1 = (float)K1h[src * 64 + l];
            float d = fdot2(q01, u2h(mu.x), 0.0f);
            d = fdot2(q23, u2h(mu.y), d);
            d = fdot2(q45, u2h(mu.z), d);
            d = fdot2(q67, u2h(mu.w), d);
            hacc = fmaf(w, d, hacc);
            sk = fmaf(w, k1, sk);
        }
    }
    uint4 mo = *(const uint4*)(M1h + (size_t)n * 256 + l * 4);
    float h1 = fdot2(q01, u2h(mo.x), 0.0f);
    h1 = fdot2(q23, u2h(mo.y), h1);
    h1 = fdot2(q45, u2h(mo.z), h1);
    h1 = fdot2(q67, u2h(mo.w), h1);
    float c1 = qown * (float)K1h[n * 64 + l];
    float c2 = qown * sk;
#pragma unroll
    for (int dd = 1; dd < 8; dd <<= 1) {
        c1 += __shfl_xor(c1, dd);
        c2 += __shfl_xor(c2, dd);
    }
    float hw0 = ldf(hopwise, 0, bf), hw1 = ldf(hopwise, 1, bf), hw2 = ldf(hopwise, 2, bf);
    float e0 = 0.0f, e1 = 0.0f;
#pragma unroll
    for (int hh = 0; hh < 8; hh++) {
        e0 += __expf(ldf(headwise, hh * 2 + 0, bf));
        e1 += __expf(ldf(headwise, hh * 2 + 1, bf));
    }
    float g1 = hw1 * __expf(ldf(headwise, h * 2 + 0, bf)) / e0;
    float g2 = hw2 * __expf(ldf(headwise, h * 2 + 1, bf)) / e1;

    float hidden = hw0 * (float)Vh[n * 64 + l] + g1 * h1 / (c1 + CSTF) + g2 * hacc / (c2 + CSTF);

    float o = ldf(bo, l, bf);
#pragma unroll 16
    for (int k = 0; k < 64; k++) {
        float hk = __shfl(hidden, k);
        o += hk * ldf(Wo, k * 64 + l, bf);
    }
    if (bf) ((bf16*)out)[n * 64 + l] = __float2bfloat16(o);
    else    ((float*)out)[n * 64 + l] = o;
}

// ---------------------------------------------------------------------------
extern "C" void kernel_launch(void* const* d_in, const int* in_sizes, int n_in,
                              void* d_out, int out_size, void* d_ws, size_t ws_size,
                              hipStream_t stream) {
    const void* x        = d_in[0];
    const void* ei       = d_in[1];
    const void* Wq       = d_in[3];
    const void* bq       = d_in[4];
    const void* Wk       = d_in[5];
    const void* bk       = d_in[6];
    const void* Wv       = d_in[7];
    const void* bv       = d_in[8];
    const void* Wo       = d_in[9];
    const void* bo       = d_in[10];
    const void* hopwise  = d_in[11];
    const void* headwise = d_in[12];

    char* p = (char*)d_ws;
    auto alloc = [&](size_t bytes) {
        void* r = (void*)p;
        p += (bytes + 255) & ~(size_t)255;
        return r;
    };
    float* Q          = (float*)alloc((size_t)N_NODES * 64 * 4);
    float* deg_inv    = (float*)alloc((size_t)N_NODES * 4);
    _Float16* K0h     = (_Float16*)alloc((size_t)N_NODES * 64 * 2);
    _Float16* Vh      = (_Float16*)alloc((size_t)N_NODES * 64 * 2);
    _Float16* K1h     = (_Float16*)alloc((size_t)N_NODES * 64 * 2);
    unsigned int* M1h = (unsigned int*)alloc((size_t)N_NODES * 512 * 2);
    float* csr_w      = (float*)alloc((size_t)N_EDGES * 4);
    int* csr_src      = (int*)alloc((size_t)N_EDGES * 4);
    int* rowptr       = (int*)alloc((size_t)(N_NODES + 1) * 4);
    // single zero zone: deg | fill | cnt
    int* zz           = (int*)alloc(((size_t)2 * N_NODES + 64) * 4);
    int* deg  = zz;
    int* fill = zz + N_NODES;
    int* cnt  = zz + 2 * N_NODES;

    (void)hipMemsetAsync(zz, 0, ((size_t)2 * N_NODES + 64) * 4, stream);

    const int EB = (N_EDGES + 255) / 256;  // 1250

    k_p1<<<EB, 256, 0, stream>>>((const unsigned int*)x, ei, deg, cnt);
    k_scan<<<1, 1024, 0, stream>>>(deg, rowptr, deg_inv);
    k_p2<<<QKV_BLOCKS + EB, 256, 0, stream>>>(x, Wq, bq, Wk, bk, Wv, bv, Q, K0h, Vh,
                                              ei, deg_inv, rowptr, fill, csr_src, csr_w, cnt);
    k_hop1<<<N_NODES / 2, 128, 0, stream>>>(K0h, Vh, rowptr, csr_src, csr_w, M1h, K1h);
    k_hop2f<<<N_NODES / 2, 128, 0, stream>>>(Q, M1h, K1h, Vh, rowptr, csr_src, csr_w,
                                             Wo, bo, hopwise, headwise, d_out, cnt);
}

// Round 9
// 240.963 us; speedup vs baseline: 1.7532x; 1.1205x over previous
//
#include <hip/hip_runtime.h>
#include <hip/hip_bf16.h>

typedef __hip_bfloat16 bf16;
typedef __fp16 half2_t __attribute__((ext_vector_type(2)));
typedef float floatx2 __attribute__((ext_vector_type(2)));

#define N_NODES 20000
#define N_EDGES 320000
#define CSTF 1e-5f

#if defined(__has_builtin)
#if __has_builtin(__builtin_amdgcn_cvt_pk_fp8_f32) && __has_builtin(__builtin_amdgcn_cvt_pk_f32_fp8)
#define M1FP8 1
#endif
#if __has_builtin(__builtin_amdgcn_fdot2)
#define HAVE_FDOT2 1
#endif
#endif

__device__ __forceinline__ half2_t u2h(unsigned int u) {
    union { unsigned int u; half2_t h; } c; c.u = u; return c.h;
}
__device__ __forceinline__ unsigned int pkh(float a, float b) {
    union { __fp16 h[2]; unsigned int u; } c;
    c.h[0] = (__fp16)a; c.h[1] = (__fp16)b;
    return c.u;
}
__device__ __forceinline__ float fdot2(half2_t a, half2_t b, float c) {
#ifdef HAVE_FDOT2
    return __builtin_amdgcn_fdot2(a, b, c, false);
#else
    return fmaf((float)a.x, (float)b.x, fmaf((float)a.y, (float)b.y, c));
#endif
}
__device__ __forceinline__ int rdl(int v, int lane) { return __builtin_amdgcn_readlane(v, lane); }
__device__ __forceinline__ float rdlf(float v, int lane) {
    return __int_as_float(__builtin_amdgcn_readlane(__float_as_int(v), lane));
}

__device__ __forceinline__ float ldf(const void* p, int i, bool bf) {
    return bf ? __bfloat162float(((const bf16*)p)[i]) : ((const float*)p)[i];
}

// Per-wave int64-vs-int32 self-detection (see R7 notes).
__device__ __forceinline__ bool wave_is_i64(const void* ei, int e) {
    unsigned int hi = ((const unsigned int*)ei)[2 * e + 1];
    return !__any(hi != 0);
}

// ---------------------------------------------------------------------------
// Phase 1: in-degree count over col + sampled x-dtype detection
__global__ __launch_bounds__(256) void k_p1(const unsigned int* __restrict__ xs,
                                            const void* __restrict__ ei,
                                            int* __restrict__ deg, int* __restrict__ cnt) {
    const int e = blockIdx.x * 256 + threadIdx.x;
    bool i64 = wave_is_i64(ei, e);
    int c = i64 ? (int)((const long long*)ei)[N_EDGES + e] : ((const int*)ei)[N_EDGES + e];
    atomicAdd(&deg[c], 1);
    if (blockIdx.x < 64) {
        int t = blockIdx.x * 256 + threadIdx.x;
        int bad = 0;
        for (int i = t; i < 40000; i += 64 * 256) {
            unsigned int w = xs[i];
            if (((w >> 7)  & 0xFFu) == 0xFFu) bad++;
            if (((w >> 23) & 0xFFu) == 0xFFu) bad++;
        }
        if (bad) atomicAdd(&cnt[0], bad);
    }
}

// Exclusive scan of deg -> rowptr + deg^-0.5 (single block)
__global__ __launch_bounds__(1024) void k_scan(const int* __restrict__ deg, int* __restrict__ rowptr,
                                               float* __restrict__ deg_inv) {
    __shared__ int part[1024];
    const int t = threadIdx.x;
    const int CH = (N_NODES + 1023) / 1024;  // 20
    int base = t * CH;
    int s = 0;
    for (int i = 0; i < CH; i++) {
        int idx = base + i;
        if (idx < N_NODES) {
            int d = deg[idx];
            s += d;
            deg_inv[idx] = d > 0 ? rsqrtf((float)d) : 0.0f;
        }
    }
    part[t] = s;
    __syncthreads();
    for (int off = 1; off < 1024; off <<= 1) {
        int v = (t >= off) ? part[t - off] : 0;
        __syncthreads();
        part[t] += v;
        __syncthreads();
    }
    int ex = (t == 0) ? 0 : part[t - 1];
    for (int i = 0; i < CH; i++) {
        int idx = base + i;
        if (idx < N_NODES) { rowptr[idx] = ex; ex += deg[idx]; }
    }
    if (t == 1023) rowptr[N_NODES] = part[1023];
}

// ---------------------------------------------------------------------------
// Phase 2 (fused): blocks [0,625) QKV; blocks [625,1875) CSR fill
#define QKV_BLOCKS 625
__global__ __launch_bounds__(256) void k_p2(const void* __restrict__ x,
                                            const void* __restrict__ Wq, const void* __restrict__ bq,
                                            const void* __restrict__ Wk, const void* __restrict__ bk,
                                            const void* __restrict__ Wv, const void* __restrict__ bv,
                                            float* __restrict__ Q, _Float16* __restrict__ K0h,
                                            _Float16* __restrict__ Vh,
                                            const void* __restrict__ ei,
                                            const float* __restrict__ deg_inv,
                                            const int* __restrict__ rowptr,
                                            int* __restrict__ fill, int* __restrict__ csr_src,
                                            float* __restrict__ csr_w,
                                            const int* __restrict__ cnt) {
    __shared__ float sWq[64 * 64];
    __shared__ float sWk[64 * 64];
    __shared__ float sWv[64 * 64];
    __shared__ float sx[4][64];
    const int t = threadIdx.x;
    if (blockIdx.x >= QKV_BLOCKS) {
        const int e = (blockIdx.x - QKV_BLOCKS) * 256 + t;
        bool i64 = wave_is_i64(ei, e);
        int r, c;
        if (i64) {
            r = (int)((const long long*)ei)[e];
            c = (int)((const long long*)ei)[N_EDGES + e];
        } else {
            r = ((const int*)ei)[e];
            c = ((const int*)ei)[N_EDGES + e];
        }
        int slot = rowptr[c] + atomicAdd(&fill[c], 1);
        csr_src[slot] = r;
        csr_w[slot] = deg_inv[r] * deg_inv[c];
        return;
    }
    const bool bf = (cnt[0] < 16);
    for (int i = t; i < 4096; i += 256) {
        sWq[i] = ldf(Wq, i, bf);
        sWk[i] = ldf(Wk, i, bf);
        sWv[i] = ldf(Wv, i, bf);
    }
    __syncthreads();
    const int lane = t & 63, sub = t >> 6;
    const float bqv = ldf(bq, lane, bf), bkv = ldf(bk, lane, bf), bvv = ldf(bv, lane, bf);
    const int npb = (N_NODES + QKV_BLOCKS - 1) / QKV_BLOCKS;  // 32
    const int n0 = blockIdx.x * npb;
    const int n1 = min(n0 + npb, N_NODES);
    for (int nb = n0; nb < n1; nb += 4) {
        int n = nb + sub;
        __syncthreads();
        if (n < n1) sx[sub][lane] = ldf(x, n * 64 + lane, bf);
        __syncthreads();
        if (n < n1) {
            float q = bqv, k = bkv, v = bvv;
#pragma unroll 16
            for (int kk = 0; kk < 64; kk++) {
                float xv = sx[sub][kk];
                q += xv * sWq[kk * 64 + lane];
                k += xv * sWk[kk * 64 + lane];
                v += xv * sWv[kk * 64 + lane];
            }
            Q[n * 64 + lane]   = q > 0.0f ? q + 1.0f : __expf(q);
            K0h[n * 64 + lane] = (_Float16)(k > 0.0f ? k + 1.0f : __expf(k));
            Vh[n * 64 + lane]  = (_Float16)v;
        }
    }
}

// ---------------------------------------------------------------------------
// M1 store helpers: fp8 (e4m3, node stride 128 uints) or f16 fallback (256)
#ifdef M1FP8
#define M1_STRIDE 128
#define M1_LANE   2
#else
#define M1_STRIDE 256
#define M1_LANE   4
#endif

// Hop 1. One node per wave, 128-thr blocks. Lane l = (h = l>>3, j = l&7).
//   M1t[n][h][j][i] = sum_e w * K0[src,h,i] * V[src,h,j]  (fp32 acc)
// Inner loop manually 4-wide batched: 12 loads issued before compute.
__global__ __launch_bounds__(128) void k_hop1(const _Float16* __restrict__ K0h,
                                              const _Float16* __restrict__ Vh,
                                              const int* __restrict__ rowptr,
                                              const int* __restrict__ csr_src,
                                              const float* __restrict__ csr_w,
                                              unsigned int* __restrict__ M1h,
                                              _Float16* __restrict__ K1h) {
    const int l = threadIdx.x & 63;
    const int n = blockIdx.x * 2 + (threadIdx.x >> 6);
    const int hb = l & 56;
    float acc[8] = {0, 0, 0, 0, 0, 0, 0, 0};
    float kacc = 0.0f;
    const int s0 = rowptr[n], s1 = rowptr[n + 1];

#define H1_BODY(KU, VO, KO, EE)                                            \
    {                                                                      \
        float w = rdlf(wv, EE);                                            \
        half2_t p0 = u2h(KU.x), p1 = u2h(KU.y), p2 = u2h(KU.z), p3 = u2h(KU.w); \
        float wvv = w * (float)VO;                                         \
        acc[0] = fmaf(wvv, (float)p0.x, acc[0]); acc[1] = fmaf(wvv, (float)p0.y, acc[1]); \
        acc[2] = fmaf(wvv, (float)p1.x, acc[2]); acc[3] = fmaf(wvv, (float)p1.y, acc[3]); \
        acc[4] = fmaf(wvv, (float)p2.x, acc[4]); acc[5] = fmaf(wvv, (float)p2.y, acc[5]); \
        acc[6] = fmaf(wvv, (float)p3.x, acc[6]); acc[7] = fmaf(wvv, (float)p3.y, acc[7]); \
        kacc = fmaf(w, (float)KO, kacc);                                   \
    }

    for (int c = s0; c < s1; c += 64) {
        const int m = min(64, s1 - c);
        const int idx = c + (l < m ? l : m - 1);
        const int srcv = csr_src[idx];
        const float wv = csr_w[idx];
        int e = 0;
        for (; e + 4 <= m; e += 4) {
            int sA = rdl(srcv, e), sB = rdl(srcv, e + 1), sC = rdl(srcv, e + 2), sD = rdl(srcv, e + 3);
            uint4 kA = *(const uint4*)(K0h + sA * 64 + hb);
            uint4 kB = *(const uint4*)(K0h + sB * 64 + hb);
            uint4 kC = *(const uint4*)(K0h + sC * 64 + hb);
            uint4 kD = *(const uint4*)(K0h + sD * 64 + hb);
            __fp16 vA = Vh[sA * 64 + l], vB = Vh[sB * 64 + l], vC = Vh[sC * 64 + l], vD = Vh[sD * 64 + l];
            __fp16 oA = K0h[sA * 64 + l], oB = K0h[sB * 64 + l], oC = K0h[sC * 64 + l], oD = K0h[sD * 64 + l];
            H1_BODY(kA, vA, oA, e)
            H1_BODY(kB, vB, oB, e + 1)
            H1_BODY(kC, vC, oC, e + 2)
            H1_BODY(kD, vD, oD, e + 3)
        }
        for (; e < m; e++) {
            int sA = rdl(srcv, e);
            uint4 kA = *(const uint4*)(K0h + sA * 64 + hb);
            __fp16 vA = Vh[sA * 64 + l];
            __fp16 oA = K0h[sA * 64 + l];
            H1_BODY(kA, vA, oA, e)
        }
    }
#undef H1_BODY

#ifdef M1FP8
    unsigned int w0 = 0, w1 = 0;
    w0 = __builtin_amdgcn_cvt_pk_fp8_f32(acc[0], acc[1], w0, false);
    w0 = __builtin_amdgcn_cvt_pk_fp8_f32(acc[2], acc[3], w0, true);
    w1 = __builtin_amdgcn_cvt_pk_fp8_f32(acc[4], acc[5], w1, false);
    w1 = __builtin_amdgcn_cvt_pk_fp8_f32(acc[6], acc[7], w1, true);
    uint2 o2; o2.x = w0; o2.y = w1;
    *(uint2*)(M1h + (size_t)n * M1_STRIDE + l * M1_LANE) = o2;
#else
    uint4 o;
    o.x = pkh(acc[0], acc[1]); o.y = pkh(acc[2], acc[3]);
    o.z = pkh(acc[4], acc[5]); o.w = pkh(acc[6], acc[7]);
    *(uint4*)(M1h + (size_t)n * M1_STRIDE + l * M1_LANE) = o;
#endif
    K1h[n * 64 + l] = (_Float16)kacc;
}

// ---------------------------------------------------------------------------
// Hop 2 + finalize. One node per wave, 128-thr blocks. Lane l = (h, j').
// M1 row gathered as fp8 (8 B/lane), decoded with v_cvt_pk_f32_fp8.
__global__ __launch_bounds__(128) void k_hop2f(const float* __restrict__ Q,
                                               const unsigned int* __restrict__ M1h,
                                               const _Float16* __restrict__ K1h,
                                               const _Float16* __restrict__ Vh,
                                               const int* __restrict__ rowptr,
                                               const int* __restrict__ csr_src,
                                               const float* __restrict__ csr_w,
                                               const void* __restrict__ Wo, const void* __restrict__ bo,
                                               const void* __restrict__ hopwise,
                                               const void* __restrict__ headwise,
                                               void* __restrict__ out, const int* __restrict__ cnt) {
    const bool bf = (cnt[0] < 16);
    const int l = threadIdx.x & 63;
    const int n = blockIdx.x * 2 + (threadIdx.x >> 6);
    const int hb = l & 56, h = l >> 3;
    const float4 qa = *(const float4*)(Q + n * 64 + hb);
    const float4 qb = *(const float4*)(Q + n * 64 + hb + 4);
    const float qown = Q[n * 64 + l];
    float hacc = 0.0f, sk = 0.0f;
    const int s0 = rowptr[n], s1 = rowptr[n + 1];

#ifdef M1FP8
#define H2_DOT(MU, DST)                                                    \
    {                                                                      \
        floatx2 a0 = __builtin_amdgcn_cvt_pk_f32_fp8(MU.x, false);         \
        floatx2 a1 = __builtin_amdgcn_cvt_pk_f32_fp8(MU.x, true);          \
        floatx2 a2 = __builtin_amdgcn_cvt_pk_f32_fp8(MU.y, false);         \
        floatx2 a3 = __builtin_amdgcn_cvt_pk_f32_fp8(MU.y, true);          \
        DST = qa.x * a0.x;                                                 \
        DST = fmaf(qa.y, a0.y, DST); DST = fmaf(qa.z, a1.x, DST);          \
        DST = fmaf(qa.w, a1.y, DST); DST = fmaf(qb.x, a2.x, DST);          \
        DST = fmaf(qb.y, a2.y, DST); DST = fmaf(qb.z, a3.x, DST);          \
        DST = fmaf(qb.w, a3.y, DST);                                       \
    }
    typedef uint2 m1vec;
#else
    const half2_t q01 = u2h(pkh(qa.x, qa.y));
    const half2_t q23 = u2h(pkh(qa.z, qa.w));
    const half2_t q45 = u2h(pkh(qb.x, qb.y));
    const half2_t q67 = u2h(pkh(qb.z, qb.w));
#define H2_DOT(MU, DST)                                                    \
    {                                                                      \
        DST = fdot2(q01, u2h(MU.x), 0.0f);                                 \
        DST = fdot2(q23, u2h(MU.y), DST);                                  \
        DST = fdot2(q45, u2h(MU.z), DST);                                  \
        DST = fdot2(q67, u2h(MU.w), DST);                                  \
    }
    typedef uint4 m1vec;
#endif

    for (int c = s0; c < s1; c += 64) {
        const int m = min(64, s1 - c);
        const int idx = c + (l < m ? l : m - 1);
        const int srcv = csr_src[idx];
        const float wv = csr_w[idx];
        int e = 0;
        for (; e + 4 <= m; e += 4) {
            int sA = rdl(srcv, e), sB = rdl(srcv, e + 1), sC = rdl(srcv, e + 2), sD = rdl(srcv, e + 3);
            m1vec mA = *(const m1vec*)(M1h + (size_t)sA * M1_STRIDE + l * M1_LANE);
            m1vec mB = *(const m1vec*)(M1h + (size_t)sB * M1_STRIDE + l * M1_LANE);
            m1vec mC = *(const m1vec*)(M1h + (size_t)sC * M1_STRIDE + l * M1_LANE);
            m1vec mD = *(const m1vec*)(M1h + (size_t)sD * M1_STRIDE + l * M1_LANE);
            __fp16 kA = K1h[sA * 64 + l], kB = K1h[sB * 64 + l], kC = K1h[sC * 64 + l], kD = K1h[sD * 64 + l];
            float d;
            H2_DOT(mA, d) { float w = rdlf(wv, e);     hacc = fmaf(w, d, hacc); sk = fmaf(w, (float)kA, sk); }
            H2_DOT(mB, d) { float w = rdlf(wv, e + 1); hacc = fmaf(w, d, hacc); sk = fmaf(w, (float)kB, sk); }
            H2_DOT(mC, d) { float w = rdlf(wv, e + 2); hacc = fmaf(w, d, hacc); sk = fmaf(w, (float)kC, sk); }
            H2_DOT(mD, d) { float w = rdlf(wv, e + 3); hacc = fmaf(w, d, hacc); sk = fmaf(w, (float)kD, sk); }
        }
        for (; e < m; e++) {
            int sA = rdl(srcv, e);
            m1vec mA = *(const m1vec*)(M1h + (size_t)sA * M1_STRIDE + l * M1_LANE);
            __fp16 kA = K1h[sA * 64 + l];
            float d;
            H2_DOT(mA, d) { float w = rdlf(wv, e); hacc = fmaf(w, d, hacc); sk = fmaf(w, (float)kA, sk); }
        }
    }
    // own-node H1 / C1
    m1vec mo = *(const m1vec*)(M1h + (size_t)n * M1_STRIDE + l * M1_LANE);
    float h1;
    H2_DOT(mo, h1)
#undef H2_DOT
    float c1 = qown * (float)K1h[n * 64 + l];
    float c2 = qown * sk;
#pragma unroll
    for (int dd = 1; dd < 8; dd <<= 1) {
        c1 += __shfl_xor(c1, dd);
        c2 += __shfl_xor(c2, dd);
    }
    float hw0 = ldf(hopwise, 0, bf), hw1 = ldf(hopwise, 1, bf), hw2 = ldf(hopwise, 2, bf);
    float e0 = 0.0f, e1 = 0.0f;
#pragma unroll
    for (int hh = 0; hh < 8; hh++) {
        e0 += __expf(ldf(headwise, hh * 2 + 0, bf));
        e1 += __expf(ldf(headwise, hh * 2 + 1, bf));
    }
    float g1 = hw1 * __expf(ldf(headwise, h * 2 + 0, bf)) / e0;
    float g2 = hw2 * __expf(ldf(headwise, h * 2 + 1, bf)) / e1;

    float hidden = hw0 * (float)Vh[n * 64 + l] + g1 * h1 / (c1 + CSTF) + g2 * hacc / (c2 + CSTF);

    float o = ldf(bo, l, bf);
#pragma unroll 16
    for (int k = 0; k < 64; k++) {
        float hk = __shfl(hidden, k);
        o += hk * ldf(Wo, k * 64 + l, bf);
    }
    if (bf) ((bf16*)out)[n * 64 + l] = __float2bfloat16(o);
    else    ((float*)out)[n * 64 + l] = o;
}

// ---------------------------------------------------------------------------
extern "C" void kernel_launch(void* const* d_in, const int* in_sizes, int n_in,
                              void* d_out, int out_size, void* d_ws, size_t ws_size,
                              hipStream_t stream) {
    const void* x        = d_in[0];
    const void* ei       = d_in[1];
    const void* Wq       = d_in[3];
    const void* bq       = d_in[4];
    const void* Wk       = d_in[5];
    const void* bk       = d_in[6];
    const void* Wv       = d_in[7];
    const void* bv       = d_in[8];
    const void* Wo       = d_in[9];
    const void* bo       = d_in[10];
    const void* hopwise  = d_in[11];
    const void* headwise = d_in[12];

    char* p = (char*)d_ws;
    auto alloc = [&](size_t bytes) {
        void* r = (void*)p;
        p += (bytes + 255) & ~(size_t)255;
        return r;
    };
    float* Q          = (float*)alloc((size_t)N_NODES * 64 * 4);
    float* deg_inv    = (float*)alloc((size_t)N_NODES * 4);
    _Float16* K0h     = (_Float16*)alloc((size_t)N_NODES * 64 * 2);
    _Float16* Vh      = (_Float16*)alloc((size_t)N_NODES * 64 * 2);
    _Float16* K1h     = (_Float16*)alloc((size_t)N_NODES * 64 * 2);
    unsigned int* M1h = (unsigned int*)alloc((size_t)N_NODES * 1024);  // covers fp8 or f16 layout
    float* csr_w      = (float*)alloc((size_t)N_EDGES * 4);
    int* csr_src      = (int*)alloc((size_t)N_EDGES * 4);
    int* rowptr       = (int*)alloc((size_t)(N_NODES + 1) * 4);
    int* zz           = (int*)alloc(((size_t)2 * N_NODES + 64) * 4);
    int* deg  = zz;
    int* fill = zz + N_NODES;
    int* cnt  = zz + 2 * N_NODES;

    (void)hipMemsetAsync(zz, 0, ((size_t)2 * N_NODES + 64) * 4, stream);

    const int EB = (N_EDGES + 255) / 256;  // 1250

    k_p1<<<EB, 256, 0, stream>>>((const unsigned int*)x, ei, deg, cnt);
    k_scan<<<1, 1024, 0, stream>>>(deg, rowptr, deg_inv);
    k_p2<<<QKV_BLOCKS + EB, 256, 0, stream>>>(x, Wq, bq, Wk, bk, Wv, bv, Q, K0h, Vh,
                                              ei, deg_inv, rowptr, fill, csr_src, csr_w, cnt);
    k_hop1<<<N_NODES / 2, 128, 0, stream>>>(K0h, Vh, rowptr, csr_src, csr_w, M1h, K1h);
    k_hop2f<<<N_NODES / 2, 128, 0, stream>>>(Q, M1h, K1h, Vh, rowptr, csr_src, csr_w,
                                             Wo, bo, hopwise, headwise, d_out, cnt);
}